// Round 7
// baseline (321.710 us; speedup 1.0000x reference)
//
#include <hip/hip_runtime.h>
#include <hip/hip_bf16.h>
#include <math.h>

// ---- problem constants ----
#define BB 2
#define HH 16
#define NN 1024
#define CC 1024
#define DD 64
#define NPAST 8192
#define NANCH 1024
#define CBUD 4096
#define NKEEP 3072
#define NCAND 8192
#define BH 32

// tiled bf16 layout: K-chunk tile = 128 rows x 64 k x 2B = 16384 bytes
#define TILEB 16384

// ---- d_out layout (floats) ----
#define OUT_SZ   (BB*NN*CC)
#define KNEW_OFF ((size_t)OUT_SZ)
#define KNEW_SZ  ((size_t)BH*CBUD*DD)
#define VNEW_OFF (KNEW_OFF + KNEW_SZ)
#define AVG_OFF  (VNEW_OFF + KNEW_SZ)

// ---- workspace layout (float offsets), with overlays ----
#define WS_KF   ((size_t)0)            // 2097152 f
#define WS_VF   ((size_t)2097152)     // 2097152 f
#define WS_VTS  ((size_t)0)            // bf16 V^T swizzled tiles overlay (after gather)
#define WS_XT   ((size_t)4194304)     // x tiled bf16: 1048576 f
#define WS_OT   ((size_t)4194304)     // o tiled bf16 (overlay XT)
#define WS_WQVT ((size_t)5242880)     // w(Q,V) tiled bf16: 1048576 f
#define WS_WPT  ((size_t)5242880)     // proj_w tiled bf16 (overlay)
#define WS_QB   ((size_t)6291456)     // q bf16: 1048576 f
#define WS_MD   ((size_t)7340032)     // 2048 f
#define WS_SC   ((size_t)7342080)     // scores 262144 f; ML overlay after topk
#define WS_ML   WS_SC                  // (m,l) partials: 2*32*1024 float2 = 131072 f
#define WS_BS   ((size_t)7604224)     // 64 f
#define WS_SEL  ((size_t)7604288)     // 98304 ints -> ends 7702592
#define WS_MDP  ((size_t)7702592)     // mean_dir partials [32][8][64] = 16384 f
#define WS_BSP  ((size_t)7718976)     // score-sum partials [32][8] = 256 f
// end = 7719232 floats = 30.9 MB

typedef __attribute__((ext_vector_type(8))) short short8;
typedef __attribute__((ext_vector_type(4))) float f32x4;

typedef unsigned int __attribute__((address_space(3))) lds_uint;
typedef unsigned int __attribute__((address_space(1))) glb_uint;

__device__ __forceinline__ void gload16(const void* g, void* l) {
    __builtin_amdgcn_global_load_lds((const glb_uint*)g, (lds_uint*)l, 16, 0, 0);
}

__device__ inline unsigned short f2bf(float f) {
    unsigned u = __float_as_uint(f);
    unsigned r = (u + 0x7FFFu + ((u >> 16) & 1u)) >> 16;
    return (unsigned short)r;
}
__device__ inline unsigned cvtpk(float a, float b) {
    __hip_bfloat162 h = __float22bfloat162_rn(make_float2(a, b));
    return *reinterpret_cast<unsigned*>(&h);
}
__device__ __forceinline__ float fexp2(float x) {
#if __has_builtin(__builtin_amdgcn_exp2f)
    return __builtin_amdgcn_exp2f(x);
#else
    return exp2f(x);
#endif
}
__device__ __forceinline__ float bf2f(unsigned short u) {
    return __uint_as_float((unsigned)u << 16);
}

// ============================================================
// converters: fp32 row-major -> tiled swizzled bf16
// ============================================================
__global__ __launch_bounds__(256) void conv_tile(const float* __restrict__ src,
                                                 unsigned short* __restrict__ dst)
{
    int gid = blockIdx.x * 256 + threadIdx.x;
    int r = gid >> 7, k0 = (gid & 127) * 8;
    float4 a = *(const float4*)&src[(size_t)r * 1024 + k0];
    float4 b = *(const float4*)&src[(size_t)r * 1024 + k0 + 4];
    uint4 u;
    u.x = cvtpk(a.x, a.y); u.y = cvtpk(a.z, a.w);
    u.z = cvtpk(b.x, b.y); u.w = cvtpk(b.z, b.w);
    size_t tile = (size_t)(r >> 7) * 16 + (k0 >> 6);
    int inner = (((r & 127) * 128 + (k0 & 63) * 2)) ^ ((r & 7) << 4);
    *(uint4*)((char*)dst + tile * TILEB + inner) = u;
}

__global__ __launch_bounds__(256) void conv_wqv(const float* __restrict__ src,
                                                unsigned short* __restrict__ dst)
{
    int gid = blockIdx.x * 256 + threadIdx.x;
    int n = gid >> 7, k0 = (gid & 127) * 8;
    int srow = (n < 1024) ? n : n + 1024;
    float4 a = *(const float4*)&src[(size_t)srow * 1024 + k0];
    float4 b = *(const float4*)&src[(size_t)srow * 1024 + k0 + 4];
    uint4 u;
    u.x = cvtpk(a.x, a.y); u.y = cvtpk(a.z, a.w);
    u.z = cvtpk(b.x, b.y); u.w = cvtpk(b.z, b.w);
    size_t tile = (size_t)(n >> 7) * 16 + (k0 >> 6);
    int inner = (((n & 127) * 128 + (k0 & 63) * 2)) ^ ((n & 7) << 4);
    *(uint4*)((char*)dst + tile * TILEB + inner) = u;
}

// ============================================================
// fp32 GEMM for K-third (precision-critical ranking path).
// ============================================================
__global__ __launch_bounds__(256) void kf_gemm(const float* __restrict__ x,
                                               const float* __restrict__ w,
                                               const float* __restrict__ bias,
                                               float* __restrict__ ws)
{
    __shared__ float As[16][68];
    __shared__ float Bs[16][68];
    int tid = threadIdx.x;
    int m0 = blockIdx.y * 64;
    int n0 = blockIdx.x * 64;
    int tx = tid & 15, ty = tid >> 4;
    int lr = tid >> 2;
    int lk = (tid & 3) * 4;
    float acc[4][4] = {{0.f}};

    float4 a = *(const float4*)&x[(size_t)(m0 + lr) * CC + lk];
    float4 b = *(const float4*)&w[(size_t)(1024 + n0 + lr) * CC + lk];

    for (int k0 = 0; k0 < CC; k0 += 16) {
        __syncthreads();
        As[lk+0][lr] = a.x; As[lk+1][lr] = a.y; As[lk+2][lr] = a.z; As[lk+3][lr] = a.w;
        Bs[lk+0][lr] = b.x; Bs[lk+1][lr] = b.y; Bs[lk+2][lr] = b.z; Bs[lk+3][lr] = b.w;
        __syncthreads();
        if (k0 + 16 < CC) {
            a = *(const float4*)&x[(size_t)(m0 + lr) * CC + k0 + 16 + lk];
            b = *(const float4*)&w[(size_t)(1024 + n0 + lr) * CC + k0 + 16 + lk];
        }
        float tacc[4][4] = {{0.f}};
        #pragma unroll
        for (int kk = 0; kk < 16; ++kk) {
            float4 a4 = *(const float4*)&As[kk][ty*4];
            float4 b4 = *(const float4*)&Bs[kk][tx*4];
            float av[4] = {a4.x, a4.y, a4.z, a4.w};
            float bv[4] = {b4.x, b4.y, b4.z, b4.w};
            #pragma unroll
            for (int i = 0; i < 4; ++i)
                #pragma unroll
                for (int j = 0; j < 4; ++j)
                    tacc[i][j] += av[i] * bv[j];
        }
        #pragma unroll
        for (int i = 0; i < 4; ++i)
            #pragma unroll
            for (int j = 0; j < 4; ++j)
                acc[i][j] += tacc[i][j];
    }

    int cn0 = n0 + tx * 4;
    int h = cn0 >> 6, dd0 = cn0 & 63;
    float4 b4 = *(const float4*)&bias[1024 + cn0];
    float* kf = ws + WS_KF;
    #pragma unroll
    for (int i = 0; i < 4; ++i) {
        int m = m0 + ty * 4 + i;
        int b2 = m >> 10, n = m & 1023;
        float4 t;
        t.x = acc[i][0] + b4.x; t.y = acc[i][1] + b4.y;
        t.z = acc[i][2] + b4.z; t.w = acc[i][3] + b4.w;
        *(float4*)&kf[(((size_t)b2*HH + h)*NN + n)*DD + dd0] = t;
    }
}

// ============================================================
// bf16 MFMA GEMM, 128x128 tile, BK=64 (unchanged from r6)
// ============================================================
template<int MODE>
__global__ __launch_bounds__(256) void mfma_gemm(const unsigned short* __restrict__ At,
                                                 const unsigned short* __restrict__ Bt,
                                                 const float* __restrict__ bias,
                                                 float* __restrict__ outp)
{
    __shared__ char lds[131072];
    int tid = threadIdx.x;
    int w = tid >> 6, lane = tid & 63;
    int g = lane >> 4, r16 = lane & 15;
    int wr = w >> 1, wc = w & 1;
    int bm = blockIdx.y, bn = blockIdx.x;
    const int KB = 16;

    f32x4 acc[4][4];
    #pragma unroll
    for (int i = 0; i < 4; ++i)
        #pragma unroll
        for (int j = 0; j < 4; ++j) acc[i][j] = 0.f;

    const char* Abase = (const char*)At + (size_t)bm * KB * TILEB;
    const char* Bbase = (const char*)Bt + (size_t)bn * KB * TILEB;

    #pragma unroll
    for (int i = 0; i < 4; ++i) {
        gload16(Abase + (size_t)w*4096 + i*1024 + lane*16, lds + w*4096 + i*1024);
        gload16(Bbase + (size_t)w*4096 + i*1024 + lane*16, lds + TILEB + w*4096 + i*1024);
    }
    asm volatile("s_waitcnt vmcnt(0)" ::: "memory");
    __syncthreads();

    int cur = 0;
    for (int kb = 0; kb < KB; ++kb) {
        char* Acur = lds + cur * (2*TILEB);
        char* Bcur = Acur + TILEB;
        if (kb + 1 < KB) {
            char* Anxt = lds + (cur ^ 1) * (2*TILEB);
            char* Bnxt = Anxt + TILEB;
            const char* an = Abase + (size_t)(kb+1)*TILEB + w*4096;
            const char* bsrc = Bbase + (size_t)(kb+1)*TILEB + w*4096;
            #pragma unroll
            for (int i = 0; i < 4; ++i) {
                gload16(an + i*1024 + lane*16, Anxt + w*4096 + i*1024);
                gload16(bsrc + i*1024 + lane*16, Bnxt + w*4096 + i*1024);
            }
        }
        short8 a0[4], a1[4], b0[4], b1[4];
        #pragma unroll
        for (int mi = 0; mi < 4; ++mi) {
            int row = wr*64 + mi*16 + r16;
            int sw = (row & 7) << 4;
            a0[mi] = *(const short8*)(Acur + ((row*128 + g*16) ^ sw));
            a1[mi] = *(const short8*)(Acur + ((row*128 + 64 + g*16) ^ sw));
        }
        #pragma unroll
        for (int ni = 0; ni < 4; ++ni) {
            int row = wc*64 + ni*16 + r16;
            int sw = (row & 7) << 4;
            b0[ni] = *(const short8*)(Bcur + ((row*128 + g*16) ^ sw));
            b1[ni] = *(const short8*)(Bcur + ((row*128 + 64 + g*16) ^ sw));
        }
        __builtin_amdgcn_s_setprio(1);
        #pragma unroll
        for (int mi = 0; mi < 4; ++mi)
            #pragma unroll
            for (int ni = 0; ni < 4; ++ni) {
                acc[mi][ni] = __builtin_amdgcn_mfma_f32_16x16x32_bf16(a0[mi], b0[ni], acc[mi][ni], 0, 0, 0);
                acc[mi][ni] = __builtin_amdgcn_mfma_f32_16x16x32_bf16(a1[mi], b1[ni], acc[mi][ni], 0, 0, 0);
            }
        __builtin_amdgcn_s_setprio(0);
        asm volatile("s_waitcnt vmcnt(0)" ::: "memory");
        __syncthreads();
        cur ^= 1;
    }

    int nq = bn*128 + wc*64;
    float bv[4];
    #pragma unroll
    for (int ni = 0; ni < 4; ++ni) {
        int n = nq + ni*16 + r16;
        bv[ni] = (MODE == 0) ? bias[(n < 1024) ? n : (n + 1024)] : bias[n];
    }
    #pragma unroll
    for (int mi = 0; mi < 4; ++mi) {
        #pragma unroll
        for (int rr = 0; rr < 4; ++rr) {
            int ml = wr*64 + mi*16 + 4*g + rr;
            int mg = bm*128 + ml;
            int bb = mg >> 10, tok = mg & 1023;
            #pragma unroll
            for (int ni = 0; ni < 4; ++ni) {
                int n = nq + ni*16 + r16;
                float v = acc[mi][ni][rr] + bv[ni];
                if (MODE == 0) {
                    if (n < 1024) {
                        unsigned short* qb = (unsigned short*)(outp + WS_QB);
                        int hh = n >> 6, d = n & 63;
                        qb[(((size_t)bb*16 + hh)*1024 + tok)*64 + d] = f2bf(v);
                    } else {
                        float* vf = outp + WS_VF;
                        int hh = (n - 1024) >> 6, d = n & 63;
                        vf[(((size_t)bb*16 + hh)*1024 + tok)*64 + d] = v;
                    }
                } else {
                    outp[(size_t)mg*1024 + n] = v;
                }
            }
        }
    }
}

// ============================================================
// mean_dir / scores partials (unchanged from r6)
// ============================================================
__global__ __launch_bounds__(256) void meandir_part(const float* __restrict__ past_k,
                                                    float* __restrict__ ws)
{
    int bh = blockIdx.x, seg = blockIdx.y, tid = threadIdx.x;
    const float* kpast = past_k + (size_t)bh * NPAST * DD;
    const float* knew  = ws + WS_KF + (size_t)bh * NN * DD;
    float dir[64];
    #pragma unroll
    for (int i = 0; i < 64; ++i) dir[i] = 0.f;

    int j0 = seg * 1024;
    for (int jj = tid; jj < 1024; jj += 256) {
        int pos = NANCH + j0 + jj;
        const float* row = (pos < NPAST) ? (kpast + (size_t)pos * DD)
                                         : (knew + (size_t)(pos - NPAST) * DD);
        float v[64]; float ss = 0.f;
        #pragma unroll
        for (int g = 0; g < 16; ++g) {
            float4 t = *(const float4*)&row[g*4];
            v[4*g]=t.x; v[4*g+1]=t.y; v[4*g+2]=t.z; v[4*g+3]=t.w;
            ss += t.x*t.x + t.y*t.y + t.z*t.z + t.w*t.w;
        }
        float inv = 1.0f / (sqrtf(ss) + 1e-6f);
        #pragma unroll
        for (int i = 0; i < 64; ++i) dir[i] += v[i] * inv;
    }
    #pragma unroll
    for (int i = 0; i < 64; ++i)
        for (int off = 32; off; off >>= 1) dir[i] += __shfl_xor(dir[i], off);

    __shared__ float sdir[4][64];
    int lane = tid & 63, wid = tid >> 6;
    if (lane == 0) {
        #pragma unroll
        for (int i = 0; i < 64; ++i) sdir[wid][i] = dir[i];
    }
    __syncthreads();
    if (tid < 64) {
        float s = sdir[0][tid] + sdir[1][tid] + sdir[2][tid] + sdir[3][tid];
        ws[WS_MDP + ((size_t)bh*8 + seg)*DD + tid] = s;
    }
}

__global__ void meandir_red(float* __restrict__ ws)
{
    int bh = blockIdx.x, tid = threadIdx.x;
    float s = 0.f;
    #pragma unroll
    for (int seg = 0; seg < 8; ++seg)
        s += ws[WS_MDP + ((size_t)bh*8 + seg)*DD + tid];
    ws[WS_MD + (size_t)bh*DD + tid] = s * (1.0f / (float)NCAND);
}

__global__ __launch_bounds__(256) void scores_part(const float* __restrict__ past_k,
                                                   float* __restrict__ ws)
{
    __shared__ float md[64];
    __shared__ float sred[4];
    int bh = blockIdx.x, seg = blockIdx.y, tid = threadIdx.x;
    if (tid < 64) md[tid] = ws[WS_MD + (size_t)bh*DD + tid];
    __syncthreads();
    const float* kpast = past_k + (size_t)bh * NPAST * DD;
    const float* knew  = ws + WS_KF + (size_t)bh * NN * DD;
    float ssum = 0.f;
    int j0 = seg * 1024;
    for (int jj = tid; jj < 1024; jj += 256) {
        int j = j0 + jj;
        int pos = NANCH + j;
        const float* row = (pos < NPAST) ? (kpast + (size_t)pos * DD)
                                         : (knew + (size_t)(pos - NPAST) * DD);
        float ss = 0.f, dp = 0.f;
        #pragma unroll
        for (int g = 0; g < 16; ++g) {
            float4 t = *(const float4*)&row[g*4];
            ss += t.x*t.x + t.y*t.y + t.z*t.z + t.w*t.w;
            dp += t.x*md[4*g] + t.y*md[4*g+1] + t.z*md[4*g+2] + t.w*md[4*g+3];
        }
        float sc = dp / (sqrtf(ss) + 1e-6f);
        ws[WS_SC + (size_t)bh*NCAND + j] = sc;
        ssum += sc;
    }
    for (int off = 32; off; off >>= 1) ssum += __shfl_xor(ssum, off);
    int lane = tid & 63, wid = tid >> 6;
    if (lane == 0) sred[wid] = ssum;
    __syncthreads();
    if (tid == 0)
        ws[WS_BSP + (size_t)bh*8 + seg] = sred[0] + sred[1] + sred[2] + sred[3];
}

__global__ void avg_k(const float* __restrict__ ws, float* __restrict__ dout)
{
    __shared__ float red[4];
    int tid = threadIdx.x;
    float v = ws[WS_BSP + tid];
    for (int off = 32; off; off >>= 1) v += __shfl_xor(v, off);
    int lane = tid & 63, wid = tid >> 6;
    if (lane == 0) red[wid] = v;
    __syncthreads();
    if (tid == 0)
        dout[AVG_OFF] = (red[0]+red[1]+red[2]+red[3]) * (1.0f / ((float)BH * (float)NCAND));
}

// ============================================================
// topk: byte-histogram radix threshold + stable compaction
// ============================================================
__global__ __launch_bounds__(1024) void topk_k(float* __restrict__ ws, int* __restrict__ sel)
{
    __shared__ unsigned keys[NCAND];
    __shared__ int hist[256];
    __shared__ int red[16];
    __shared__ int red2[16];
    __shared__ int bcast;
    __shared__ unsigned bbyte;
    int bh = blockIdx.x, tid = threadIdx.x;
    int lane = tid & 63, wid = tid >> 6;

    for (int j = tid; j < NCAND; j += 1024) {
        unsigned u = __float_as_uint(ws[WS_SC + (size_t)bh*NCAND + j]);
        u ^= (u & 0x80000000u) ? 0xFFFFFFFFu : 0x80000000u;
        keys[j] = u;
    }
    __syncthreads();

    int rem = NKEEP;
    unsigned prefix = 0;
    #pragma unroll
    for (int pass = 0; pass < 4; ++pass) {
        int shift = 24 - 8*pass;
        if (tid < 256) hist[tid] = 0;
        __syncthreads();
        unsigned himask = (pass == 0) ? 0u : (0xFFFFFFFFu << (shift + 8));
        for (int j = tid; j < NCAND; j += 1024) {
            unsigned k = keys[j];
            if ((k & himask) == prefix)
                atomicAdd(&hist[(k >> shift) & 255], 1);
        }
        __syncthreads();
        if (tid == 0) {
            int cum = 0, b = 0;
            for (; b < 255; ++b) {
                if (rem <= cum + hist[b]) break;
                cum += hist[b];
            }
            bcast = cum;
            bbyte = (unsigned)b;
        }
        __syncthreads();
        rem -= bcast;
        prefix |= (bbyte << shift);
        __syncthreads();
    }
    unsigned T = prefix;

    {
        int cnt = 0;
        for (int j = tid; j < NCAND; j += 1024) cnt += (int)(keys[j] < T);
        for (int off = 32; off; off >>= 1) cnt += __shfl_xor(cnt, off);
        if (lane == 0) red[wid] = cnt;
        __syncthreads();
        if (tid == 0) { int c = 0; for (int i = 0; i < 16; ++i) c += red[i]; bcast = c; }
        __syncthreads();
    }
    int c_less = bcast;
    int ttie = NKEEP - c_less;

    int base = tid * 8;
    unsigned kv[8]; int lcnt = 0, ecnt = 0;
    #pragma unroll
    for (int i = 0; i < 8; ++i) {
        kv[i] = keys[base + i];
        lcnt += (int)(kv[i] < T);
        ecnt += (int)(kv[i] == T);
    }
    int li = lcnt, ei = ecnt;
    for (int off = 1; off < 64; off <<= 1) {
        int tl = __shfl_up(li, off);
        int te = __shfl_up(ei, off);
        if (lane >= off) { li += tl; ei += te; }
    }
    __syncthreads();
    if (lane == 63) { red[wid] = li; red2[wid] = ei; }
    __syncthreads();
    int lb = 0, eb = 0;
    for (int w = 0; w < wid; ++w) { lb += red[w]; eb += red2[w]; }
    lb += li - lcnt; eb += ei - ecnt;
    #pragma unroll
    for (int i = 0; i < 8; ++i) {
        bool less = kv[i] < T, eq = kv[i] == T;
        if (less || (eq && eb < ttie)) {
            int pos = lb + (eb < ttie ? eb : ttie);
            sel[(size_t)bh*NKEEP + pos] = base + i;
        }
        lb += (int)less; eb += (int)eq;
    }
}

// ============================================================
// gather k_new / v_new (fp32, exact) into d_out
// ============================================================
__global__ __launch_bounds__(256) void gather_k(const float* __restrict__ past_k,
                                                const float* __restrict__ past_v,
                                                const float* __restrict__ ws,
                                                const int* __restrict__ sel,
                                                float* __restrict__ dout)
{
    int gid = blockIdx.x * 256 + threadIdx.x;
    int row = gid >> 4, lane = gid & 15;
    int bh = row >> 12, r = row & 4095;
    int pos = (r < NANCH) ? r : (NANCH + sel[(size_t)bh*NKEEP + (r - NANCH)]);
    const float *kr, *vr;
    if (pos < NPAST) {
        kr = past_k + ((size_t)bh*NPAST + pos) * DD;
        vr = past_v + ((size_t)bh*NPAST + pos) * DD;
    } else {
        kr = ws + WS_KF + ((size_t)bh*NN + (pos - NPAST)) * DD;
        vr = ws + WS_VF + ((size_t)bh*NN + (pos - NPAST)) * DD;
    }
    float4 kq = *(const float4*)&kr[lane*4];
    float4 vq = *(const float4*)&vr[lane*4];
    *(float4*)&dout[KNEW_OFF + ((size_t)bh*CBUD + r)*DD + lane*4] = kq;
    *(float4*)&dout[VNEW_OFF + ((size_t)bh*CBUD + r)*DD + lane*4] = vq;
}

// ============================================================
// V^T bf16 swizzled tiles: tile (bh,kt) 8KB; row=d, addr =
// d*128 + (kk*2) ^ ((d&7)<<4). Staged in attn by linear gload16.
// ============================================================
__global__ __launch_bounds__(256) void vtrans_k(const float* __restrict__ dout,
                                                unsigned short* __restrict__ vt)
{
    __shared__ unsigned short S[64][65];
    int bh = blockIdx.x >> 6, kt = blockIdx.x & 63;
    int c0 = kt * 64;
    int tid = threadIdx.x;
    int r = tid >> 2, c4 = (tid & 3) * 16;
    const float* src = dout + VNEW_OFF + ((size_t)bh*CBUD + c0 + r)*DD + c4;
    #pragma unroll
    for (int i = 0; i < 4; ++i) {
        float4 f = *(const float4*)&src[i*4];
        S[r][c4 + i*4 + 0] = f2bf(f.x);
        S[r][c4 + i*4 + 1] = f2bf(f.y);
        S[r][c4 + i*4 + 2] = f2bf(f.z);
        S[r][c4 + i*4 + 3] = f2bf(f.w);
    }
    __syncthreads();
    int d = r, k4 = c4;
    uint4 u0, u1;
    u0.x = (unsigned)S[k4+0][d] | ((unsigned)S[k4+1][d] << 16);
    u0.y = (unsigned)S[k4+2][d] | ((unsigned)S[k4+3][d] << 16);
    u0.z = (unsigned)S[k4+4][d] | ((unsigned)S[k4+5][d] << 16);
    u0.w = (unsigned)S[k4+6][d] | ((unsigned)S[k4+7][d] << 16);
    u1.x = (unsigned)S[k4+8][d] | ((unsigned)S[k4+9][d] << 16);
    u1.y = (unsigned)S[k4+10][d] | ((unsigned)S[k4+11][d] << 16);
    u1.z = (unsigned)S[k4+12][d] | ((unsigned)S[k4+13][d] << 16);
    u1.w = (unsigned)S[k4+14][d] | ((unsigned)S[k4+15][d] << 16);
    size_t tbase = ((size_t)bh*64 + kt) * 8192;
    int sw = (d & 7) << 4;
    *(uint4*)((char*)vt + tbase + ((d*128 + k4*2)      ^ sw)) = u0;
    *(uint4*)((char*)vt + tbase + ((d*128 + k4*2 + 16) ^ sw)) = u1;
}

// ============================================================
// KV-split flash attention (half = 32 tiles). Unnormalized bf16
// partial O -> d_out out-region; (m,l) fp32 -> WS_ML.
// V staged via linear gload16 from pre-swizzled tiles; K staged
// reg->cvtpk->ds_write. One barrier/tile.
// ============================================================
__global__ __launch_bounds__(256) void attn_split(const unsigned short* __restrict__ qb,
                                                  float* __restrict__ dout,
                                                  const unsigned short* __restrict__ vt,
                                                  float* __restrict__ ws)
{
    __shared__ char kls[2][8192];
    __shared__ char vls[2][8192];
    __shared__ char pls[4][2048];

    const float SCL = 0.125f * 1.44269504089f;
    const float THR = 11.5415603f;

    int orig = blockIdx.x;
    int bid = (orig & 7) * 128 + (orig >> 3);      // 1024 = 8*128 XCD chunks
    int bh = bid >> 5;
    int qt = (bid >> 1) & 15;
    int half = bid & 1;
    int tid = threadIdx.x;
    int w = tid >> 6, lane = tid & 63;
    int g = lane >> 4, r16 = lane & 15;
    int q0 = qt * 64 + w * 16;
    int t0 = half * 32;

    const unsigned short* qrow = qb + ((size_t)bh*NN + q0 + r16) * DD;
    short8 qa0 = *(const short8*)&qrow[8*g];
    short8 qa1 = *(const short8*)&qrow[32 + 8*g];

    const float* kf = dout + KNEW_OFF + (size_t)bh * CBUD * DD;
    const char* vtt = (const char*)vt + (size_t)bh * 64 * 8192;
    char* plw = pls[w];
    int psw = (r16 & 7) << 4;

    // K staging map: 8 threads/row, 16B each; two row-slots per thread
    int srA = tid >> 3;                 // rows 0..31
    int srB = srA + 32;                 // rows 32..63
    int scb = (tid & 7) * 16;
    int d0  = scb >> 1;
    int sdA = (srA*128 + scb) ^ ((srA & 7) << 4);
    int sdB = (srB*128 + scb) ^ ((srB & 7) << 4);

    f32x4 accd[4];
    #pragma unroll
    for (int dt = 0; dt < 4; ++dt) accd[dt] = 0.f;
    float m = -3.0e38f, l = 0.f;

    // prologue: stage tile t0 into buf 0
    {
        gload16(vtt + (size_t)t0*8192 + tid*16,        vls[0] + tid*16);
        gload16(vtt + (size_t)t0*8192 + 4096 + tid*16, vls[0] + 4096 + tid*16);
        const float* ksA = kf + ((size_t)t0*64 + srA) * DD + d0;
        const float* ksB = kf + ((size_t)t0*64 + srB) * DD + d0;
        float4 a0 = *(const float4*)ksA, a1 = *(const float4*)(ksA + 4);
        float4 b0 = *(const float4*)ksB, b1 = *(const float4*)(ksB + 4);
        uint4 kuA, kuB;
        kuA.x = cvtpk(a0.x,a0.y); kuA.y = cvtpk(a0.z,a0.w);
        kuA.z = cvtpk(a1.x,a1.y); kuA.w = cvtpk(a1.z,a1.w);
        kuB.x = cvtpk(b0.x,b0.y); kuB.y = cvtpk(b0.z,b0.w);
        kuB.z = cvtpk(b1.x,b1.y); kuB.w = cvtpk(b1.z,b1.w);
        *(uint4*)&kls[0][sdA] = kuA; *(uint4*)&kls[0][sdB] = kuB;
    }
    __syncthreads();

    int cur = 0;
    for (int t = t0; t < t0 + 32; ++t) {
        float4 a0, a1, b0, b1;
        bool more = (t + 1 < t0 + 32);
        if (more) {
            // V: DMA into next buffer (linear copy of pre-swizzled tile)
            gload16(vtt + (size_t)(t+1)*8192 + tid*16,        vls[cur^1] + tid*16);
            gload16(vtt + (size_t)(t+1)*8192 + 4096 + tid*16, vls[cur^1] + 4096 + tid*16);
            // K: issue reg loads early
            const float* ksA = kf + ((size_t)(t+1)*64 + srA) * DD + d0;
            const float* ksB = kf + ((size_t)(t+1)*64 + srB) * DD + d0;
            a0 = *(const float4*)ksA; a1 = *(const float4*)(ksA + 4);
            b0 = *(const float4*)ksB; b1 = *(const float4*)(ksB + 4);
        }

        const char* kb = kls[cur];
        f32x4 sacc[4];
        #pragma unroll
        for (int t4 = 0; t4 < 4; ++t4) sacc[t4] = 0.f;
        __builtin_amdgcn_s_setprio(1);
        #pragma unroll
        for (int t4 = 0; t4 < 4; ++t4) {
            int row = 16*t4 + r16;
            int sw = (r16 & 7) << 4;
            short8 ka0 = *(const short8*)(kb + ((row*128 + g*16) ^ sw));
            short8 ka1 = *(const short8*)(kb + ((row*128 + 64 + g*16) ^ sw));
            sacc[t4] = __builtin_amdgcn_mfma_f32_16x16x32_bf16(ka0, qa0, sacc[t4], 0, 0, 0);
            sacc[t4] = __builtin_amdgcn_mfma_f32_16x16x32_bf16(ka1, qa1, sacc[t4], 0, 0, 0);
        }
        __builtin_amdgcn_s_setprio(0);

        float sv[4][4];
        float smax = -3.0e38f;
        #pragma unroll
        for (int t4 = 0; t4 < 4; ++t4)
            #pragma unroll
            for (int rr = 0; rr < 4; ++rr) {
                sv[t4][rr] = sacc[t4][rr] * SCL;
                smax = fmaxf(smax, sv[t4][rr]);
            }
        smax = fmaxf(smax, __shfl_xor(smax, 16));
        smax = fmaxf(smax, __shfl_xor(smax, 32));

        if (!__all(smax <= m + THR)) {
            float mnew = fmaxf(m, smax);
            float rs = fexp2(m - mnew);
            l *= rs;
            m = mnew;
            float rq0 = __shfl(rs, 20*g + 0);
            float rq1 = __shfl(rs, 20*g + 1);
            float rq2 = __shfl(rs, 20*g + 2);
            float rq3 = __shfl(rs, 20*g + 3);
            #pragma unroll
            for (int dt = 0; dt < 4; ++dt) {
                accd[dt][0] *= rq0; accd[dt][1] *= rq1;
                accd[dt][2] *= rq2; accd[dt][3] *= rq3;
            }
        }

        float ps = 0.f;
        float p[4][4];
        #pragma unroll
        for (int t4 = 0; t4 < 4; ++t4)
            #pragma unroll
            for (int rr = 0; rr < 4; ++rr) {
                p[t4][rr] = fexp2(sv[t4][rr] - m);
                ps += p[t4][rr];
            }
        #pragma unroll
        for (int t4 = 0; t4 < 4; ++t4) {
            uint2 u;
            u.x = cvtpk(p[t4][0], p[t4][1]);
            u.y = cvtpk(p[t4][2], p[t4][3]);
            int cb = (16*t4 + 4*g) * 2;
            *(uint2*)&plw[(r16*128 + cb) ^ psw] = u;
        }
        ps += __shfl_xor(ps, 16);
        ps += __shfl_xor(ps, 32);
        l += ps;

        short8 pa0 = *(const short8*)&plw[(r16*128 + 16*g)      ^ psw];
        short8 pa1 = *(const short8*)&plw[(r16*128 + 64 + 16*g) ^ psw];
        const char* vb = vls[cur];
        __builtin_amdgcn_s_setprio(1);
        #pragma unroll
        for (int dt = 0; dt < 4; ++dt) {
            int row = dt*16 + r16;
            int sw = (r16 & 7) << 4;
            short8 vb0 = *(const short8*)(vb + ((row*128 + g*16) ^ sw));
            short8 vb1 = *(const short8*)(vb + ((row*128 + 64 + g*16) ^ sw));
            accd[dt] = __builtin_amdgcn_mfma_f32_16x16x32_bf16(pa0, vb0, accd[dt], 0, 0, 0);
            accd[dt] = __builtin_amdgcn_mfma_f32_16x16x32_bf16(pa1, vb1, accd[dt], 0, 0, 0);
        }
        __builtin_amdgcn_s_setprio(0);

        if (more) {
            uint4 kuA, kuB;
            kuA.x = cvtpk(a0.x,a0.y); kuA.y = cvtpk(a0.z,a0.w);
            kuA.z = cvtpk(a1.x,a1.y); kuA.w = cvtpk(a1.z,a1.w);
            kuB.x = cvtpk(b0.x,b0.y); kuB.y = cvtpk(b0.z,b0.w);
            kuB.z = cvtpk(b1.x,b1.y); kuB.w = cvtpk(b1.z,b1.w);
            *(uint4*)&kls[cur^1][sdA] = kuA; *(uint4*)&kls[cur^1][sdB] = kuB;
        }
        __syncthreads();   // drains gload_lds (vmcnt) + ds_writes
        cur ^= 1;
    }

    // epilogue: unnormalized partial O (bf16) + (m,l)
    unsigned short* po = (unsigned short*)dout;   // out region reused as scratch
    size_t pq = ((size_t)half*BH + bh)*NN;
    #pragma unroll
    for (int dt = 0; dt < 4; ++dt)
        #pragma unroll
        for (int rr = 0; rr < 4; ++rr)
            po[(pq + q0 + 4*g + rr)*DD + dt*16 + r16] = f2bf(accd[dt][rr]);
    if (g == 0) {
        float2* mlp = (float2*)(ws + WS_ML);
        mlp[pq + q0 + r16] = make_float2(m, l);
    }
}

// ============================================================
// combine halves -> OT (proj-input swizzled tiles)
// ============================================================
__global__ __launch_bounds__(256) void combine_k(const float* __restrict__ dout,
                                                 const float* __restrict__ ws,
                                                 unsigned short* __restrict__ ot)
{
    int gid = blockIdx.x * 256 + threadIdx.x;   // 262144
    int d8 = gid & 7;
    int q  = (gid >> 3) & 1023;
    int bh = gid >> 13;

    const float2* mlp = (const float2*)(ws + WS_ML);
    float2 ml0 = mlp[((size_t)0*BH + bh)*NN + q];
    float2 ml1 = mlp[((size_t)1*BH + bh)*NN + q];
    float mm = fmaxf(ml0.x, ml1.x);
    float w0 = fexp2(ml0.x - mm), w1 = fexp2(ml1.x - mm);
    float inv = 1.0f / (w0*ml0.y + w1*ml1.y);
    float s0 = w0 * inv, s1 = w1 * inv;

    const unsigned short* po = (const unsigned short*)dout;
    const unsigned short* a0 = po + (((size_t)0*BH + bh)*NN + q)*DD + d8*8;
    const unsigned short* a1 = po + (((size_t)1*BH + bh)*NN + q)*DD + d8*8;
    uint4 u0 = *(const uint4*)a0;
    uint4 u1 = *(const uint4*)a1;

    unsigned r[4];
    const unsigned* p0 = (const unsigned*)&u0;
    const unsigned* p1 = (const unsigned*)&u1;
    #pragma unroll
    for (int i = 0; i < 4; ++i) {
        float lo = bf2f((unsigned short)(p0[i] & 0xFFFF)) * s0
                 + bf2f((unsigned short)(p1[i] & 0xFFFF)) * s1;
        float hi = bf2f((unsigned short)(p0[i] >> 16)) * s0
                 + bf2f((unsigned short)(p1[i] >> 16)) * s1;
        r[i] = cvtpk(lo, hi);
    }

    int b = bh >> 4, h = bh & 15;
    int mrow = b*1024 + q;
    size_t tile = (size_t)(mrow >> 7) * 16 + h;
    int inner = ((mrow & 127)*128 + d8*16) ^ ((mrow & 7) << 4);
    uint4 out4; out4.x = r[0]; out4.y = r[1]; out4.z = r[2]; out4.w = r[3];
    *(uint4*)((char*)ot + tile*TILEB + inner) = out4;
}

// ============================================================
extern "C" void kernel_launch(void* const* d_in, const int* in_sizes, int n_in,
                              void* d_out, int out_size, void* d_ws, size_t ws_size,
                              hipStream_t stream)
{
    (void)in_sizes; (void)n_in; (void)out_size; (void)ws_size;
    const float* x      = (const float*)d_in[0];
    const float* past_k = (const float*)d_in[1];
    const float* past_v = (const float*)d_in[2];
    const float* qkv_w  = (const float*)d_in[3];
    const float* qkv_b  = (const float*)d_in[4];
    const float* proj_w = (const float*)d_in[5];
    const float* proj_b = (const float*)d_in[6];
    float* out = (float*)d_out;
    float* ws  = (float*)d_ws;
    int*   sel = (int*)(ws + WS_SEL);
    unsigned short* xt   = (unsigned short*)(ws + WS_XT);
    unsigned short* wqvt = (unsigned short*)(ws + WS_WQVT);
    unsigned short* wpt  = (unsigned short*)(ws + WS_WPT);
    unsigned short* qbp  = (unsigned short*)(ws + WS_QB);
    unsigned short* vtp  = (unsigned short*)(ws + WS_VTS);
    unsigned short* otp  = (unsigned short*)(ws + WS_OT);

    conv_tile<<<1024, 256, 0, stream>>>(x, xt);
    conv_wqv<<<1024, 256, 0, stream>>>(qkv_w, wqvt);
    kf_gemm<<<dim3(16, 32), 256, 0, stream>>>(x, qkv_w, qkv_b, ws);
    mfma_gemm<0><<<dim3(16, 16), 256, 0, stream>>>(xt, wqvt, qkv_b, ws);
    meandir_part<<<dim3(32, 8), 256, 0, stream>>>(past_k, ws);
    meandir_red<<<32, 64, 0, stream>>>(ws);
    scores_part<<<dim3(32, 8), 256, 0, stream>>>(past_k, ws);
    avg_k<<<1, 256, 0, stream>>>(ws, out);
    topk_k<<<32, 1024, 0, stream>>>(ws, sel);
    gather_k<<<8192, 256, 0, stream>>>(past_k, past_v, ws, sel, out);
    vtrans_k<<<2048, 256, 0, stream>>>(out, vtp);
    conv_tile<<<512, 256, 0, stream>>>(proj_w, wpt);
    attn_split<<<1024, 256, 0, stream>>>(qbp, out, vtp, ws);
    combine_k<<<1024, 256, 0, stream>>>(out, ws, otp);
    mfma_gemm<1><<<dim3(8, 16), 256, 0, stream>>>(otp, wpt, proj_b, out);
}

// Round 8
// 296.084 us; speedup vs baseline: 1.0865x; 1.0865x over previous
//
#include <hip/hip_runtime.h>
#include <hip/hip_bf16.h>
#include <math.h>

// ---- problem constants ----
#define BB 2
#define HH 16
#define NN 1024
#define CC 1024
#define DD 64
#define NPAST 8192
#define NANCH 1024
#define CBUD 4096
#define NKEEP 3072
#define NCAND 8192
#define BH 32

// tiled bf16 layout: K-chunk tile = 128 rows x 64 k x 2B = 16384 bytes
#define TILEB 16384

// ---- d_out layout (floats) ----
#define OUT_SZ   (BB*NN*CC)
#define KNEW_OFF ((size_t)OUT_SZ)
#define KNEW_SZ  ((size_t)BH*CBUD*DD)
#define VNEW_OFF (KNEW_OFF + KNEW_SZ)
#define AVG_OFF  (VNEW_OFF + KNEW_SZ)

// ---- workspace layout (float offsets), with overlays ----
#define WS_KF   ((size_t)0)            // 2097152 f
#define WS_VF   ((size_t)2097152)     // 2097152 f
#define WS_VTS  ((size_t)0)            // bf16 V^T swizzled tiles overlay (after gather)
#define WS_XT   ((size_t)4194304)     // x tiled bf16: 1048576 f
#define WS_OT   ((size_t)4194304)     // o tiled bf16 (overlay XT)
#define WS_WQVT ((size_t)5242880)     // w(Q,V) tiled bf16: 1048576 f
#define WS_WPT  ((size_t)5242880)     // proj_w tiled bf16 (overlay)
#define WS_QB   ((size_t)6291456)     // q bf16 (PRE-SCALED by 0.125*log2e): 1048576 f
#define WS_MD   ((size_t)7340032)     // 2048 f
#define WS_SC   ((size_t)7342080)     // scores 262144 f
#define WS_BS   ((size_t)7604224)     // 64 f
#define WS_SEL  ((size_t)7604288)     // 98304 ints -> ends 7702592
#define WS_MDP  ((size_t)7702592)     // mean_dir partials [32][8][64] = 16384 f
#define WS_BSP  ((size_t)7718976)     // score-sum partials [32][8] = 256 f
// end = 7719232 floats = 30.9 MB

typedef __attribute__((ext_vector_type(8))) short short8;
typedef __attribute__((ext_vector_type(4))) float f32x4;

typedef unsigned int __attribute__((address_space(3))) lds_uint;
typedef unsigned int __attribute__((address_space(1))) glb_uint;

__device__ __forceinline__ void gload16(const void* g, void* l) {
    __builtin_amdgcn_global_load_lds((const glb_uint*)g, (lds_uint*)l, 16, 0, 0);
}

__device__ inline unsigned short f2bf(float f) {
    unsigned u = __float_as_uint(f);
    unsigned r = (u + 0x7FFFu + ((u >> 16) & 1u)) >> 16;
    return (unsigned short)r;
}
__device__ inline unsigned cvtpk(float a, float b) {
    __hip_bfloat162 h = __float22bfloat162_rn(make_float2(a, b));
    return *reinterpret_cast<unsigned*>(&h);
}
__device__ __forceinline__ float fexp2(float x) {
#if __has_builtin(__builtin_amdgcn_exp2f)
    return __builtin_amdgcn_exp2f(x);
#else
    return exp2f(x);
#endif
}

// ============================================================
// converters: fp32 row-major -> tiled swizzled bf16
// ============================================================
__global__ __launch_bounds__(256) void conv_tile(const float* __restrict__ src,
                                                 unsigned short* __restrict__ dst)
{
    int gid = blockIdx.x * 256 + threadIdx.x;
    int r = gid >> 7, k0 = (gid & 127) * 8;
    float4 a = *(const float4*)&src[(size_t)r * 1024 + k0];
    float4 b = *(const float4*)&src[(size_t)r * 1024 + k0 + 4];
    uint4 u;
    u.x = cvtpk(a.x, a.y); u.y = cvtpk(a.z, a.w);
    u.z = cvtpk(b.x, b.y); u.w = cvtpk(b.z, b.w);
    size_t tile = (size_t)(r >> 7) * 16 + (k0 >> 6);
    int inner = (((r & 127) * 128 + (k0 & 63) * 2)) ^ ((r & 7) << 4);
    *(uint4*)((char*)dst + tile * TILEB + inner) = u;
}

__global__ __launch_bounds__(256) void conv_wqv(const float* __restrict__ src,
                                                unsigned short* __restrict__ dst)
{
    int gid = blockIdx.x * 256 + threadIdx.x;
    int n = gid >> 7, k0 = (gid & 127) * 8;
    int srow = (n < 1024) ? n : n + 1024;
    float4 a = *(const float4*)&src[(size_t)srow * 1024 + k0];
    float4 b = *(const float4*)&src[(size_t)srow * 1024 + k0 + 4];
    uint4 u;
    u.x = cvtpk(a.x, a.y); u.y = cvtpk(a.z, a.w);
    u.z = cvtpk(b.x, b.y); u.w = cvtpk(b.z, b.w);
    size_t tile = (size_t)(n >> 7) * 16 + (k0 >> 6);
    int inner = (((n & 127) * 128 + (k0 & 63) * 2)) ^ ((n & 7) << 4);
    *(uint4*)((char*)dst + tile * TILEB + inner) = u;
}

// ============================================================
// fp32 GEMM for K-third (precision-critical ranking path).
// ============================================================
__global__ __launch_bounds__(256) void kf_gemm(const float* __restrict__ x,
                                               const float* __restrict__ w,
                                               const float* __restrict__ bias,
                                               float* __restrict__ ws)
{
    __shared__ float As[16][68];
    __shared__ float Bs[16][68];
    int tid = threadIdx.x;
    int m0 = blockIdx.y * 64;
    int n0 = blockIdx.x * 64;
    int tx = tid & 15, ty = tid >> 4;
    int lr = tid >> 2;
    int lk = (tid & 3) * 4;
    float acc[4][4] = {{0.f}};

    float4 a = *(const float4*)&x[(size_t)(m0 + lr) * CC + lk];
    float4 b = *(const float4*)&w[(size_t)(1024 + n0 + lr) * CC + lk];

    for (int k0 = 0; k0 < CC; k0 += 16) {
        __syncthreads();
        As[lk+0][lr] = a.x; As[lk+1][lr] = a.y; As[lk+2][lr] = a.z; As[lk+3][lr] = a.w;
        Bs[lk+0][lr] = b.x; Bs[lk+1][lr] = b.y; Bs[lk+2][lr] = b.z; Bs[lk+3][lr] = b.w;
        __syncthreads();
        if (k0 + 16 < CC) {
            a = *(const float4*)&x[(size_t)(m0 + lr) * CC + k0 + 16 + lk];
            b = *(const float4*)&w[(size_t)(1024 + n0 + lr) * CC + k0 + 16 + lk];
        }
        float tacc[4][4] = {{0.f}};
        #pragma unroll
        for (int kk = 0; kk < 16; ++kk) {
            float4 a4 = *(const float4*)&As[kk][ty*4];
            float4 b4 = *(const float4*)&Bs[kk][tx*4];
            float av[4] = {a4.x, a4.y, a4.z, a4.w};
            float bv[4] = {b4.x, b4.y, b4.z, b4.w};
            #pragma unroll
            for (int i = 0; i < 4; ++i)
                #pragma unroll
                for (int j = 0; j < 4; ++j)
                    tacc[i][j] += av[i] * bv[j];
        }
        #pragma unroll
        for (int i = 0; i < 4; ++i)
            #pragma unroll
            for (int j = 0; j < 4; ++j)
                acc[i][j] += tacc[i][j];
    }

    int cn0 = n0 + tx * 4;
    int h = cn0 >> 6, dd0 = cn0 & 63;
    float4 b4 = *(const float4*)&bias[1024 + cn0];
    float* kf = ws + WS_KF;
    #pragma unroll
    for (int i = 0; i < 4; ++i) {
        int m = m0 + ty * 4 + i;
        int b2 = m >> 10, n = m & 1023;
        float4 t;
        t.x = acc[i][0] + b4.x; t.y = acc[i][1] + b4.y;
        t.z = acc[i][2] + b4.z; t.w = acc[i][3] + b4.w;
        *(float4*)&kf[(((size_t)b2*HH + h)*NN + n)*DD + dd0] = t;
    }
}

// ============================================================
// bf16 MFMA GEMM, 128x128 tile, BK=64. MODE 0: QV epilogue
// (Q -> bf16 qb PRE-SCALED, V -> fp32 vf). MODE 1: proj -> dout.
// ============================================================
template<int MODE>
__global__ __launch_bounds__(256) void mfma_gemm(const unsigned short* __restrict__ At,
                                                 const unsigned short* __restrict__ Bt,
                                                 const float* __restrict__ bias,
                                                 float* __restrict__ outp)
{
    __shared__ char lds[131072];
    int tid = threadIdx.x;
    int w = tid >> 6, lane = tid & 63;
    int g = lane >> 4, r16 = lane & 15;
    int wr = w >> 1, wc = w & 1;
    int bm = blockIdx.y, bn = blockIdx.x;
    const int KB = 16;
    const float QSCL = 0.125f * 1.44269504089f;

    f32x4 acc[4][4];
    #pragma unroll
    for (int i = 0; i < 4; ++i)
        #pragma unroll
        for (int j = 0; j < 4; ++j) acc[i][j] = 0.f;

    const char* Abase = (const char*)At + (size_t)bm * KB * TILEB;
    const char* Bbase = (const char*)Bt + (size_t)bn * KB * TILEB;

    #pragma unroll
    for (int i = 0; i < 4; ++i) {
        gload16(Abase + (size_t)w*4096 + i*1024 + lane*16, lds + w*4096 + i*1024);
        gload16(Bbase + (size_t)w*4096 + i*1024 + lane*16, lds + TILEB + w*4096 + i*1024);
    }
    asm volatile("s_waitcnt vmcnt(0)" ::: "memory");
    __syncthreads();

    int cur = 0;
    for (int kb = 0; kb < KB; ++kb) {
        char* Acur = lds + cur * (2*TILEB);
        char* Bcur = Acur + TILEB;
        if (kb + 1 < KB) {
            char* Anxt = lds + (cur ^ 1) * (2*TILEB);
            char* Bnxt = Anxt + TILEB;
            const char* an = Abase + (size_t)(kb+1)*TILEB + w*4096;
            const char* bsrc = Bbase + (size_t)(kb+1)*TILEB + w*4096;
            #pragma unroll
            for (int i = 0; i < 4; ++i) {
                gload16(an + i*1024 + lane*16, Anxt + w*4096 + i*1024);
                gload16(bsrc + i*1024 + lane*16, Bnxt + w*4096 + i*1024);
            }
        }
        short8 a0[4], a1[4], b0[4], b1[4];
        #pragma unroll
        for (int mi = 0; mi < 4; ++mi) {
            int row = wr*64 + mi*16 + r16;
            int sw = (row & 7) << 4;
            a0[mi] = *(const short8*)(Acur + ((row*128 + g*16) ^ sw));
            a1[mi] = *(const short8*)(Acur + ((row*128 + 64 + g*16) ^ sw));
        }
        #pragma unroll
        for (int ni = 0; ni < 4; ++ni) {
            int row = wc*64 + ni*16 + r16;
            int sw = (row & 7) << 4;
            b0[ni] = *(const short8*)(Bcur + ((row*128 + g*16) ^ sw));
            b1[ni] = *(const short8*)(Bcur + ((row*128 + 64 + g*16) ^ sw));
        }
        __builtin_amdgcn_s_setprio(1);
        #pragma unroll
        for (int mi = 0; mi < 4; ++mi)
            #pragma unroll
            for (int ni = 0; ni < 4; ++ni) {
                acc[mi][ni] = __builtin_amdgcn_mfma_f32_16x16x32_bf16(a0[mi], b0[ni], acc[mi][ni], 0, 0, 0);
                acc[mi][ni] = __builtin_amdgcn_mfma_f32_16x16x32_bf16(a1[mi], b1[ni], acc[mi][ni], 0, 0, 0);
            }
        __builtin_amdgcn_s_setprio(0);
        asm volatile("s_waitcnt vmcnt(0)" ::: "memory");
        __syncthreads();
        cur ^= 1;
    }

    int nq = bn*128 + wc*64;
    float bv[4];
    #pragma unroll
    for (int ni = 0; ni < 4; ++ni) {
        int n = nq + ni*16 + r16;
        bv[ni] = (MODE == 0) ? bias[(n < 1024) ? n : (n + 1024)] : bias[n];
    }
    #pragma unroll
    for (int mi = 0; mi < 4; ++mi) {
        #pragma unroll
        for (int rr = 0; rr < 4; ++rr) {
            int ml = wr*64 + mi*16 + 4*g + rr;
            int mg = bm*128 + ml;
            int bb = mg >> 10, tok = mg & 1023;
            #pragma unroll
            for (int ni = 0; ni < 4; ++ni) {
                int n = nq + ni*16 + r16;
                float v = acc[mi][ni][rr] + bv[ni];
                if (MODE == 0) {
                    if (n < 1024) {
                        unsigned short* qb = (unsigned short*)(outp + WS_QB);
                        int hh = n >> 6, d = n & 63;
                        qb[(((size_t)bb*16 + hh)*1024 + tok)*64 + d] = f2bf(v * QSCL);
                    } else {
                        float* vf = outp + WS_VF;
                        int hh = (n - 1024) >> 6, d = n & 63;
                        vf[(((size_t)bb*16 + hh)*1024 + tok)*64 + d] = v;
                    }
                } else {
                    outp[(size_t)mg*1024 + n] = v;
                }
            }
        }
    }
}

// ============================================================
// mean_dir / scores partials
// ============================================================
__global__ __launch_bounds__(256) void meandir_part(const float* __restrict__ past_k,
                                                    float* __restrict__ ws)
{
    int bh = blockIdx.x, seg = blockIdx.y, tid = threadIdx.x;
    const float* kpast = past_k + (size_t)bh * NPAST * DD;
    const float* knew  = ws + WS_KF + (size_t)bh * NN * DD;
    float dir[64];
    #pragma unroll
    for (int i = 0; i < 64; ++i) dir[i] = 0.f;

    int j0 = seg * 1024;
    for (int jj = tid; jj < 1024; jj += 256) {
        int pos = NANCH + j0 + jj;
        const float* row = (pos < NPAST) ? (kpast + (size_t)pos * DD)
                                         : (knew + (size_t)(pos - NPAST) * DD);
        float v[64]; float ss = 0.f;
        #pragma unroll
        for (int g = 0; g < 16; ++g) {
            float4 t = *(const float4*)&row[g*4];
            v[4*g]=t.x; v[4*g+1]=t.y; v[4*g+2]=t.z; v[4*g+3]=t.w;
            ss += t.x*t.x + t.y*t.y + t.z*t.z + t.w*t.w;
        }
        float inv = 1.0f / (sqrtf(ss) + 1e-6f);
        #pragma unroll
        for (int i = 0; i < 64; ++i) dir[i] += v[i] * inv;
    }
    #pragma unroll
    for (int i = 0; i < 64; ++i)
        for (int off = 32; off; off >>= 1) dir[i] += __shfl_xor(dir[i], off);

    __shared__ float sdir[4][64];
    int lane = tid & 63, wid = tid >> 6;
    if (lane == 0) {
        #pragma unroll
        for (int i = 0; i < 64; ++i) sdir[wid][i] = dir[i];
    }
    __syncthreads();
    if (tid < 64) {
        float s = sdir[0][tid] + sdir[1][tid] + sdir[2][tid] + sdir[3][tid];
        ws[WS_MDP + ((size_t)bh*8 + seg)*DD + tid] = s;
    }
}

__global__ void meandir_red(float* __restrict__ ws)
{
    int bh = blockIdx.x, tid = threadIdx.x;
    float s = 0.f;
    #pragma unroll
    for (int seg = 0; seg < 8; ++seg)
        s += ws[WS_MDP + ((size_t)bh*8 + seg)*DD + tid];
    ws[WS_MD + (size_t)bh*DD + tid] = s * (1.0f / (float)NCAND);
}

__global__ __launch_bounds__(256) void scores_part(const float* __restrict__ past_k,
                                                   float* __restrict__ ws)
{
    __shared__ float md[64];
    __shared__ float sred[4];
    int bh = blockIdx.x, seg = blockIdx.y, tid = threadIdx.x;
    if (tid < 64) md[tid] = ws[WS_MD + (size_t)bh*DD + tid];
    __syncthreads();
    const float* kpast = past_k + (size_t)bh * NPAST * DD;
    const float* knew  = ws + WS_KF + (size_t)bh * NN * DD;
    float ssum = 0.f;
    int j0 = seg * 1024;
    for (int jj = tid; jj < 1024; jj += 256) {
        int j = j0 + jj;
        int pos = NANCH + j;
        const float* row = (pos < NPAST) ? (kpast + (size_t)pos * DD)
                                         : (knew + (size_t)(pos - NPAST) * DD);
        float ss = 0.f, dp = 0.f;
        #pragma unroll
        for (int g = 0; g < 16; ++g) {
            float4 t = *(const float4*)&row[g*4];
            ss += t.x*t.x + t.y*t.y + t.z*t.z + t.w*t.w;
            dp += t.x*md[4*g] + t.y*md[4*g+1] + t.z*md[4*g+2] + t.w*md[4*g+3];
        }
        float sc = dp / (sqrtf(ss) + 1e-6f);
        ws[WS_SC + (size_t)bh*NCAND + j] = sc;
        ssum += sc;
    }
    for (int off = 32; off; off >>= 1) ssum += __shfl_xor(ssum, off);
    int lane = tid & 63, wid = tid >> 6;
    if (lane == 0) sred[wid] = ssum;
    __syncthreads();
    if (tid == 0)
        ws[WS_BSP + (size_t)bh*8 + seg] = sred[0] + sred[1] + sred[2] + sred[3];
}

__global__ void avg_k(const float* __restrict__ ws, float* __restrict__ dout)
{
    __shared__ float red[4];
    int tid = threadIdx.x;
    float v = ws[WS_BSP + tid];
    for (int off = 32; off; off >>= 1) v += __shfl_xor(v, off);
    int lane = tid & 63, wid = tid >> 6;
    if (lane == 0) red[wid] = v;
    __syncthreads();
    if (tid == 0)
        dout[AVG_OFF] = (red[0]+red[1]+red[2]+red[3]) * (1.0f / ((float)BH * (float)NCAND));
}

// ============================================================
// topk: byte-histogram radix threshold + stable compaction
// ============================================================
__global__ __launch_bounds__(1024) void topk_k(float* __restrict__ ws, int* __restrict__ sel)
{
    __shared__ unsigned keys[NCAND];
    __shared__ int hist[256];
    __shared__ int red[16];
    __shared__ int red2[16];
    __shared__ int bcast;
    __shared__ unsigned bbyte;
    int bh = blockIdx.x, tid = threadIdx.x;
    int lane = tid & 63, wid = tid >> 6;

    for (int j = tid; j < NCAND; j += 1024) {
        unsigned u = __float_as_uint(ws[WS_SC + (size_t)bh*NCAND + j]);
        u ^= (u & 0x80000000u) ? 0xFFFFFFFFu : 0x80000000u;
        keys[j] = u;
    }
    __syncthreads();

    int rem = NKEEP;
    unsigned prefix = 0;
    #pragma unroll
    for (int pass = 0; pass < 4; ++pass) {
        int shift = 24 - 8*pass;
        if (tid < 256) hist[tid] = 0;
        __syncthreads();
        unsigned himask = (pass == 0) ? 0u : (0xFFFFFFFFu << (shift + 8));
        for (int j = tid; j < NCAND; j += 1024) {
            unsigned k = keys[j];
            if ((k & himask) == prefix)
                atomicAdd(&hist[(k >> shift) & 255], 1);
        }
        __syncthreads();
        if (tid == 0) {
            int cum = 0, b = 0;
            for (; b < 255; ++b) {
                if (rem <= cum + hist[b]) break;
                cum += hist[b];
            }
            bcast = cum;
            bbyte = (unsigned)b;
        }
        __syncthreads();
        rem -= bcast;
        prefix |= (bbyte << shift);
        __syncthreads();
    }
    unsigned T = prefix;

    {
        int cnt = 0;
        for (int j = tid; j < NCAND; j += 1024) cnt += (int)(keys[j] < T);
        for (int off = 32; off; off >>= 1) cnt += __shfl_xor(cnt, off);
        if (lane == 0) red[wid] = cnt;
        __syncthreads();
        if (tid == 0) { int c = 0; for (int i = 0; i < 16; ++i) c += red[i]; bcast = c; }
        __syncthreads();
    }
    int c_less = bcast;
    int ttie = NKEEP - c_less;

    int base = tid * 8;
    unsigned kv[8]; int lcnt = 0, ecnt = 0;
    #pragma unroll
    for (int i = 0; i < 8; ++i) {
        kv[i] = keys[base + i];
        lcnt += (int)(kv[i] < T);
        ecnt += (int)(kv[i] == T);
    }
    int li = lcnt, ei = ecnt;
    for (int off = 1; off < 64; off <<= 1) {
        int tl = __shfl_up(li, off);
        int te = __shfl_up(ei, off);
        if (lane >= off) { li += tl; ei += te; }
    }
    __syncthreads();
    if (lane == 63) { red[wid] = li; red2[wid] = ei; }
    __syncthreads();
    int lb = 0, eb = 0;
    for (int w = 0; w < wid; ++w) { lb += red[w]; eb += red2[w]; }
    lb += li - lcnt; eb += ei - ecnt;
    #pragma unroll
    for (int i = 0; i < 8; ++i) {
        bool less = kv[i] < T, eq = kv[i] == T;
        if (less || (eq && eb < ttie)) {
            int pos = lb + (eb < ttie ? eb : ttie);
            sel[(size_t)bh*NKEEP + pos] = base + i;
        }
        lb += (int)less; eb += (int)eq;
    }
}

// ============================================================
// gather k_new / v_new (fp32, exact) into d_out
// ============================================================
__global__ __launch_bounds__(256) void gather_k(const float* __restrict__ past_k,
                                                const float* __restrict__ past_v,
                                                const float* __restrict__ ws,
                                                const int* __restrict__ sel,
                                                float* __restrict__ dout)
{
    int gid = blockIdx.x * 256 + threadIdx.x;
    int row = gid >> 4, lane = gid & 15;
    int bh = row >> 12, r = row & 4095;
    int pos = (r < NANCH) ? r : (NANCH + sel[(size_t)bh*NKEEP + (r - NANCH)]);
    const float *kr, *vr;
    if (pos < NPAST) {
        kr = past_k + ((size_t)bh*NPAST + pos) * DD;
        vr = past_v + ((size_t)bh*NPAST + pos) * DD;
    } else {
        kr = ws + WS_KF + ((size_t)bh*NN + (pos - NPAST)) * DD;
        vr = ws + WS_VF + ((size_t)bh*NN + (pos - NPAST)) * DD;
    }
    float4 kq = *(const float4*)&kr[lane*4];
    float4 vq = *(const float4*)&vr[lane*4];
    *(float4*)&dout[KNEW_OFF + ((size_t)bh*CBUD + r)*DD + lane*4] = kq;
    *(float4*)&dout[VNEW_OFF + ((size_t)bh*CBUD + r)*DD + lane*4] = vq;
}

// ============================================================
// V^T bf16 swizzled tiles: tile (bh,kt) 8KB; row=d, addr =
// d*128 + (kk*2) ^ ((d&7)<<4). Staged in attn by linear gload16.
// ============================================================
__global__ __launch_bounds__(256) void vtrans_k(const float* __restrict__ dout,
                                                unsigned short* __restrict__ vt)
{
    __shared__ unsigned short S[64][65];
    int bh = blockIdx.x >> 6, kt = blockIdx.x & 63;
    int c0 = kt * 64;
    int tid = threadIdx.x;
    int r = tid >> 2, c4 = (tid & 3) * 16;
    const float* src = dout + VNEW_OFF + ((size_t)bh*CBUD + c0 + r)*DD + c4;
    #pragma unroll
    for (int i = 0; i < 4; ++i) {
        float4 f = *(const float4*)&src[i*4];
        S[r][c4 + i*4 + 0] = f2bf(f.x);
        S[r][c4 + i*4 + 1] = f2bf(f.y);
        S[r][c4 + i*4 + 2] = f2bf(f.z);
        S[r][c4 + i*4 + 3] = f2bf(f.w);
    }
    __syncthreads();
    int d = r, k4 = c4;
    uint4 u0, u1;
    u0.x = (unsigned)S[k4+0][d] | ((unsigned)S[k4+1][d] << 16);
    u0.y = (unsigned)S[k4+2][d] | ((unsigned)S[k4+3][d] << 16);
    u0.z = (unsigned)S[k4+4][d] | ((unsigned)S[k4+5][d] << 16);
    u0.w = (unsigned)S[k4+6][d] | ((unsigned)S[k4+7][d] << 16);
    u1.x = (unsigned)S[k4+8][d] | ((unsigned)S[k4+9][d] << 16);
    u1.y = (unsigned)S[k4+10][d] | ((unsigned)S[k4+11][d] << 16);
    u1.z = (unsigned)S[k4+12][d] | ((unsigned)S[k4+13][d] << 16);
    u1.w = (unsigned)S[k4+14][d] | ((unsigned)S[k4+15][d] << 16);
    size_t tbase = ((size_t)bh*64 + kt) * 8192;
    int sw = (d & 7) << 4;
    *(uint4*)((char*)vt + tbase + ((d*128 + k4*2)      ^ sw)) = u0;
    *(uint4*)((char*)vt + tbase + ((d*128 + k4*2 + 16) ^ sw)) = u1;
}

// ============================================================
// MFMA flash attention, swapped QK^T, FIXED-MAX softmax:
// Q pre-scaled by 0.125*log2e; p = exp2(S) directly (|S|<~5 by
// norm bound). No max reduce, no rescale, l deferred to epilogue.
// V staged via gload16 DMA from pre-swizzled tiles; K reg-staged.
// 512 blocks x 4 waves x 16 q; 64 KV tiles; 1 barrier/tile.
// ============================================================
__global__ __launch_bounds__(256) void attn_mfma(const unsigned short* __restrict__ qb,
                                                 const float* __restrict__ dout,
                                                 const unsigned short* __restrict__ vt,
                                                 unsigned short* __restrict__ ot)
{
    __shared__ char kls[2][8192];
    __shared__ char vls[2][8192];
    __shared__ char pls[4][2048];

    int orig = blockIdx.x;
    int bid = (orig & 7) * 64 + (orig >> 3);
    int bh = bid >> 4, qt = bid & 15;
    int b = bh >> 4, h = bh & 15;
    int tid = threadIdx.x;
    int w = tid >> 6, lane = tid & 63;
    int g = lane >> 4, r16 = lane & 15;
    int q0 = qt * 64 + w * 16;

    const unsigned short* qrow = qb + ((size_t)bh*NN + q0 + r16) * DD;
    short8 qa0 = *(const short8*)&qrow[8*g];
    short8 qa1 = *(const short8*)&qrow[32 + 8*g];

    const float* kf = dout + KNEW_OFF + (size_t)bh * CBUD * DD;
    const char* vtt = (const char*)vt + (size_t)bh * 64 * 8192;
    char* plw = pls[w];
    int psw = (r16 & 7) << 4;

    // K staging map: 8 threads/row, 16B each; two row-slots per thread
    int srA = tid >> 3;
    int srB = srA + 32;
    int scb = (tid & 7) * 16;
    int d0  = scb >> 1;
    int sdA = (srA*128 + scb) ^ ((srA & 7) << 4);
    int sdB = (srB*128 + scb) ^ ((srB & 7) << 4);

    f32x4 accd[4];
    #pragma unroll
    for (int dt = 0; dt < 4; ++dt) accd[dt] = 0.f;
    float lsum = 0.f;

    // prologue: stage tile 0 into buf 0
    {
        gload16(vtt + tid*16,        vls[0] + tid*16);
        gload16(vtt + 4096 + tid*16, vls[0] + 4096 + tid*16);
        const float* ksA = kf + (size_t)srA * DD + d0;
        const float* ksB = kf + (size_t)srB * DD + d0;
        float4 a0 = *(const float4*)ksA, a1 = *(const float4*)(ksA + 4);
        float4 b0 = *(const float4*)ksB, b1 = *(const float4*)(ksB + 4);
        uint4 kuA, kuB;
        kuA.x = cvtpk(a0.x,a0.y); kuA.y = cvtpk(a0.z,a0.w);
        kuA.z = cvtpk(a1.x,a1.y); kuA.w = cvtpk(a1.z,a1.w);
        kuB.x = cvtpk(b0.x,b0.y); kuB.y = cvtpk(b0.z,b0.w);
        kuB.z = cvtpk(b1.x,b1.y); kuB.w = cvtpk(b1.z,b1.w);
        *(uint4*)&kls[0][sdA] = kuA; *(uint4*)&kls[0][sdB] = kuB;
    }
    __syncthreads();

    int cur = 0;
    for (int t = 0; t < 64; ++t) {
        float4 a0, a1, b0, b1;
        bool more = (t + 1 < 64);
        if (more) {
            gload16(vtt + (size_t)(t+1)*8192 + tid*16,        vls[cur^1] + tid*16);
            gload16(vtt + (size_t)(t+1)*8192 + 4096 + tid*16, vls[cur^1] + 4096 + tid*16);
            const float* ksA = kf + ((size_t)(t+1)*64 + srA) * DD + d0;
            const float* ksB = kf + ((size_t)(t+1)*64 + srB) * DD + d0;
            a0 = *(const float4*)ksA; a1 = *(const float4*)(ksA + 4);
            b0 = *(const float4*)ksB; b1 = *(const float4*)(ksB + 4);
        }

        // ---- QK^T (swapped): S^T tiles; sacc already in exp2 domain ----
        const char* kb = kls[cur];
        f32x4 sacc[4];
        #pragma unroll
        for (int t4 = 0; t4 < 4; ++t4) sacc[t4] = 0.f;
        __builtin_amdgcn_s_setprio(1);
        #pragma unroll
        for (int t4 = 0; t4 < 4; ++t4) {
            int row = 16*t4 + r16;
            int sw = (r16 & 7) << 4;
            short8 ka0 = *(const short8*)(kb + ((row*128 + g*16) ^ sw));
            short8 ka1 = *(const short8*)(kb + ((row*128 + 64 + g*16) ^ sw));
            sacc[t4] = __builtin_amdgcn_mfma_f32_16x16x32_bf16(ka0, qa0, sacc[t4], 0, 0, 0);
            sacc[t4] = __builtin_amdgcn_mfma_f32_16x16x32_bf16(ka1, qa1, sacc[t4], 0, 0, 0);
        }
        __builtin_amdgcn_s_setprio(0);

        // ---- fixed-max softmax: p = exp2(S), accumulate l per-lane ----
        float p[4][4];
        float ps = 0.f;
        #pragma unroll
        for (int t4 = 0; t4 < 4; ++t4) {
            p[t4][0] = fexp2(sacc[t4][0]);
            p[t4][1] = fexp2(sacc[t4][1]);
            p[t4][2] = fexp2(sacc[t4][2]);
            p[t4][3] = fexp2(sacc[t4][3]);
            ps += (p[t4][0] + p[t4][1]) + (p[t4][2] + p[t4][3]);
        }
        lsum += ps;
        #pragma unroll
        for (int t4 = 0; t4 < 4; ++t4) {
            uint2 u;
            u.x = cvtpk(p[t4][0], p[t4][1]);
            u.y = cvtpk(p[t4][2], p[t4][3]);
            int cb = (16*t4 + 4*g) * 2;
            *(uint2*)&plw[(r16*128 + cb) ^ psw] = u;
        }

        // ---- PV ----
        short8 pa0 = *(const short8*)&plw[(r16*128 + 16*g)      ^ psw];
        short8 pa1 = *(const short8*)&plw[(r16*128 + 64 + 16*g) ^ psw];
        const char* vb = vls[cur];
        __builtin_amdgcn_s_setprio(1);
        #pragma unroll
        for (int dt = 0; dt < 4; ++dt) {
            int row = dt*16 + r16;
            int sw = (r16 & 7) << 4;
            short8 vb0 = *(const short8*)(vb + ((row*128 + g*16) ^ sw));
            short8 vb1 = *(const short8*)(vb + ((row*128 + 64 + g*16) ^ sw));
            accd[dt] = __builtin_amdgcn_mfma_f32_16x16x32_bf16(pa0, vb0, accd[dt], 0, 0, 0);
            accd[dt] = __builtin_amdgcn_mfma_f32_16x16x32_bf16(pa1, vb1, accd[dt], 0, 0, 0);
        }
        __builtin_amdgcn_s_setprio(0);

        // ---- write next K tile, then single barrier ----
        if (more) {
            uint4 kuA, kuB;
            kuA.x = cvtpk(a0.x,a0.y); kuA.y = cvtpk(a0.z,a0.w);
            kuA.z = cvtpk(a1.x,a1.y); kuA.w = cvtpk(a1.z,a1.w);
            kuB.x = cvtpk(b0.x,b0.y); kuB.y = cvtpk(b0.z,b0.w);
            kuB.z = cvtpk(b1.x,b1.y); kuB.w = cvtpk(b1.z,b1.w);
            *(uint4*)&kls[cur^1][sdA] = kuA; *(uint4*)&kls[cur^1][sdB] = kuB;
        }
        __syncthreads();   // drains gload_lds (vmcnt) + ds_writes
        cur ^= 1;
    }

    // epilogue: one cross-lane l reduce, then normalize + OT write
    lsum += __shfl_xor(lsum, 16);
    lsum += __shfl_xor(lsum, 32);
    float ivl = 1.0f / lsum;               // valid for q = r16
    float iq[4];
    #pragma unroll
    for (int rr = 0; rr < 4; ++rr) iq[rr] = __shfl(ivl, 20*g + rr);
    #pragma unroll
    for (int dt = 0; dt < 4; ++dt) {
        #pragma unroll
        for (int rr = 0; rr < 4; ++rr) {
            int q = q0 + 4*g + rr;
            int mrow = b*1024 + q;
            int d = dt*16 + r16;
            size_t tile = (size_t)(mrow >> 7) * 16 + h;
            int inner = ((mrow & 127)*128 + d*2) ^ ((mrow & 7) << 4);
            *(unsigned short*)((char*)ot + tile*TILEB + inner) = f2bf(accd[dt][rr] * iq[rr]);
        }
    }
}

// ============================================================
extern "C" void kernel_launch(void* const* d_in, const int* in_sizes, int n_in,
                              void* d_out, int out_size, void* d_ws, size_t ws_size,
                              hipStream_t stream)
{
    (void)in_sizes; (void)n_in; (void)out_size; (void)ws_size;
    const float* x      = (const float*)d_in[0];
    const float* past_k = (const float*)d_in[1];
    const float* past_v = (const float*)d_in[2];
    const float* qkv_w  = (const float*)d_in[3];
    const float* qkv_b  = (const float*)d_in[4];
    const float* proj_w = (const float*)d_in[5];
    const float* proj_b = (const float*)d_in[6];
    float* out = (float*)d_out;
    float* ws  = (float*)d_ws;
    int*   sel = (int*)(ws + WS_SEL);
    unsigned short* xt   = (unsigned short*)(ws + WS_XT);
    unsigned short* wqvt = (unsigned short*)(ws + WS_WQVT);
    unsigned short* wpt  = (unsigned short*)(ws + WS_WPT);
    unsigned short* qbp  = (unsigned short*)(ws + WS_QB);
    unsigned short* vtp  = (unsigned short*)(ws + WS_VTS);
    unsigned short* otp  = (unsigned short*)(ws + WS_OT);

    conv_tile<<<1024, 256, 0, stream>>>(x, xt);
    conv_wqv<<<1024, 256, 0, stream>>>(qkv_w, wqvt);
    kf_gemm<<<dim3(16, 32), 256, 0, stream>>>(x, qkv_w, qkv_b, ws);
    mfma_gemm<0><<<dim3(16, 16), 256, 0, stream>>>(xt, wqvt, qkv_b, ws);
    meandir_part<<<dim3(32, 8), 256, 0, stream>>>(past_k, ws);
    meandir_red<<<32, 64, 0, stream>>>(ws);
    scores_part<<<dim3(32, 8), 256, 0, stream>>>(past_k, ws);
    avg_k<<<1, 256, 0, stream>>>(ws, out);
    topk_k<<<32, 1024, 0, stream>>>(ws, sel);
    gather_k<<<8192, 256, 0, stream>>>(past_k, past_v, ws, sel, out);
    vtrans_k<<<2048, 256, 0, stream>>>(out, vtp);
    conv_tile<<<512, 256, 0, stream>>>(proj_w, wpt);
    attn_mfma<<<512, 256, 0, stream>>>(qbp, out, vtp, otp);
    mfma_gemm<1><<<dim3(8, 16), 256, 0, stream>>>(otp, wpt, proj_b, out);
}

// Round 9
// 283.699 us; speedup vs baseline: 1.1340x; 1.0437x over previous
//
#include <hip/hip_runtime.h>
#include <hip/hip_bf16.h>
#include <math.h>

// ---- problem constants ----
#define BB 2
#define HH 16
#define NN 1024
#define CC 1024
#define DD 64
#define NPAST 8192
#define NANCH 1024
#define CBUD 4096
#define NKEEP 3072
#define NCAND 8192
#define BH 32

// tiled bf16 layout: K-chunk tile = 128 rows x 64 k x 2B = 16384 bytes
#define TILEB 16384

// ---- d_out layout (floats) ----
#define OUT_SZ   (BB*NN*CC)
#define KNEW_OFF ((size_t)OUT_SZ)
#define KNEW_SZ  ((size_t)BH*CBUD*DD)
#define VNEW_OFF (KNEW_OFF + KNEW_SZ)
#define AVG_OFF  (VNEW_OFF + KNEW_SZ)

// ---- workspace layout (float offsets), with overlays ----
#define WS_KF   ((size_t)0)            // 2097152 f
#define WS_VF   ((size_t)2097152)     // 2097152 f
#define WS_VTS  ((size_t)0)            // bf16 V^T swizzled tiles overlay (after gather)
#define WS_XT   ((size_t)4194304)     // x tiled bf16: 1048576 f
#define WS_OT   ((size_t)4194304)     // o tiled bf16 (overlay XT)
#define WS_WQVT ((size_t)5242880)     // w(Q,V) tiled bf16: 1048576 f
#define WS_WPT  ((size_t)5242880)     // proj_w tiled bf16 (overlay)
#define WS_QB   ((size_t)6291456)     // q bf16 (PRE-SCALED by 0.125*log2e): 1048576 f
#define WS_MD   ((size_t)7340032)     // 2048 f
#define WS_SC   ((size_t)7342080)     // scores 262144 f
#define WS_BS   ((size_t)7604224)     // 64 f
#define WS_SEL  ((size_t)7604288)     // 98304 ints -> ends 7702592
#define WS_MDP  ((size_t)7702592)     // mean_dir partials [32][8][64] = 16384 f
#define WS_BSP  ((size_t)7718976)     // score-sum partials [32][8] = 256 f
// end = 7719232 floats = 30.9 MB

typedef __attribute__((ext_vector_type(8))) short short8;
typedef __attribute__((ext_vector_type(4))) float f32x4;

typedef unsigned int __attribute__((address_space(3))) lds_uint;
typedef unsigned int __attribute__((address_space(1))) glb_uint;

__device__ __forceinline__ void gload16(const void* g, void* l) {
    __builtin_amdgcn_global_load_lds((const glb_uint*)g, (lds_uint*)l, 16, 0, 0);
}

__device__ inline unsigned short f2bf(float f) {
    unsigned u = __float_as_uint(f);
    unsigned r = (u + 0x7FFFu + ((u >> 16) & 1u)) >> 16;
    return (unsigned short)r;
}
__device__ inline unsigned cvtpk(float a, float b) {
    __hip_bfloat162 h = __float22bfloat162_rn(make_float2(a, b));
    return *reinterpret_cast<unsigned*>(&h);
}
__device__ __forceinline__ float fexp2(float x) {
#if __has_builtin(__builtin_amdgcn_exp2f)
    return __builtin_amdgcn_exp2f(x);
#else
    return exp2f(x);
#endif
}

// ============================================================
// merged converter: blocks <1024: x -> xt; >=1024: qkv_w(Q,V) -> wqvt
// ============================================================
__global__ __launch_bounds__(256) void conv_xw(const float* __restrict__ x,
                                               const float* __restrict__ qw,
                                               unsigned short* __restrict__ xt,
                                               unsigned short* __restrict__ wqvt)
{
    int bid = blockIdx.x;
    int gid = (bid & 1023) * 256 + threadIdx.x;
    int r = gid >> 7, k0 = (gid & 127) * 8;
    const float* src;
    unsigned short* dst;
    int srow;
    if (bid < 1024) { src = x;  dst = xt;   srow = r; }
    else            { src = qw; dst = wqvt; srow = (r < 1024) ? r : r + 1024; }
    float4 a = *(const float4*)&src[(size_t)srow * 1024 + k0];
    float4 b = *(const float4*)&src[(size_t)srow * 1024 + k0 + 4];
    uint4 u;
    u.x = cvtpk(a.x, a.y); u.y = cvtpk(a.z, a.w);
    u.z = cvtpk(b.x, b.y); u.w = cvtpk(b.z, b.w);
    size_t tile = (size_t)(r >> 7) * 16 + (k0 >> 6);
    int inner = (((r & 127) * 128 + (k0 & 63) * 2)) ^ ((r & 7) << 4);
    *(uint4*)((char*)dst + tile * TILEB + inner) = u;
}

// ============================================================
// fp32 GEMM for K-third (ranking path), double-buffered LDS,
// one barrier per K-step; accumulation order identical.
// ============================================================
__global__ __launch_bounds__(256) void kf_gemm(const float* __restrict__ x,
                                               const float* __restrict__ w,
                                               const float* __restrict__ bias,
                                               float* __restrict__ ws)
{
    __shared__ float As[2][16][68];
    __shared__ float Bs[2][16][68];
    int tid = threadIdx.x;
    int m0 = blockIdx.y * 64;
    int n0 = blockIdx.x * 64;
    int tx = tid & 15, ty = tid >> 4;
    int lr = tid >> 2;
    int lk = (tid & 3) * 4;
    float acc[4][4] = {{0.f}};

    // prologue: load + stage k0=0 into buf 0
    {
        float4 a = *(const float4*)&x[(size_t)(m0 + lr) * CC + lk];
        float4 b = *(const float4*)&w[(size_t)(1024 + n0 + lr) * CC + lk];
        As[0][lk+0][lr] = a.x; As[0][lk+1][lr] = a.y; As[0][lk+2][lr] = a.z; As[0][lk+3][lr] = a.w;
        Bs[0][lk+0][lr] = b.x; Bs[0][lk+1][lr] = b.y; Bs[0][lk+2][lr] = b.z; Bs[0][lk+3][lr] = b.w;
    }
    __syncthreads();

    int cur = 0;
    for (int k0 = 0; k0 < CC; k0 += 16) {
        float4 a, b;
        bool more = (k0 + 16 < CC);
        if (more) {
            a = *(const float4*)&x[(size_t)(m0 + lr) * CC + k0 + 16 + lk];
            b = *(const float4*)&w[(size_t)(1024 + n0 + lr) * CC + k0 + 16 + lk];
        }
        float tacc[4][4] = {{0.f}};
        #pragma unroll
        for (int kk = 0; kk < 16; ++kk) {
            float4 a4 = *(const float4*)&As[cur][kk][ty*4];
            float4 b4 = *(const float4*)&Bs[cur][kk][tx*4];
            float av[4] = {a4.x, a4.y, a4.z, a4.w};
            float bv[4] = {b4.x, b4.y, b4.z, b4.w};
            #pragma unroll
            for (int i = 0; i < 4; ++i)
                #pragma unroll
                for (int j = 0; j < 4; ++j)
                    tacc[i][j] += av[i] * bv[j];
        }
        #pragma unroll
        for (int i = 0; i < 4; ++i)
            #pragma unroll
            for (int j = 0; j < 4; ++j)
                acc[i][j] += tacc[i][j];
        if (more) {
            As[cur^1][lk+0][lr] = a.x; As[cur^1][lk+1][lr] = a.y;
            As[cur^1][lk+2][lr] = a.z; As[cur^1][lk+3][lr] = a.w;
            Bs[cur^1][lk+0][lr] = b.x; Bs[cur^1][lk+1][lr] = b.y;
            Bs[cur^1][lk+2][lr] = b.z; Bs[cur^1][lk+3][lr] = b.w;
        }
        __syncthreads();
        cur ^= 1;
    }

    int cn0 = n0 + tx * 4;
    int h = cn0 >> 6, dd0 = cn0 & 63;
    float4 b4 = *(const float4*)&bias[1024 + cn0];
    float* kf = ws + WS_KF;
    #pragma unroll
    for (int i = 0; i < 4; ++i) {
        int m = m0 + ty * 4 + i;
        int b2 = m >> 10, n = m & 1023;
        float4 t;
        t.x = acc[i][0] + b4.x; t.y = acc[i][1] + b4.y;
        t.z = acc[i][2] + b4.z; t.w = acc[i][3] + b4.w;
        *(float4*)&kf[(((size_t)b2*HH + h)*NN + n)*DD + dd0] = t;
    }
}

// ============================================================
// bf16 MFMA GEMM, 128x128 tile, BK=64. MODE 0: QV epilogue
// (Q -> bf16 qb PRE-SCALED, V -> fp32 vf). MODE 1: proj -> dout.
// ============================================================
template<int MODE>
__global__ __launch_bounds__(256) void mfma_gemm(const unsigned short* __restrict__ At,
                                                 const unsigned short* __restrict__ Bt,
                                                 const float* __restrict__ bias,
                                                 float* __restrict__ outp)
{
    __shared__ char lds[131072];
    int tid = threadIdx.x;
    int w = tid >> 6, lane = tid & 63;
    int g = lane >> 4, r16 = lane & 15;
    int wr = w >> 1, wc = w & 1;
    int bm = blockIdx.y, bn = blockIdx.x;
    const int KB = 16;
    const float QSCL = 0.125f * 1.44269504089f;

    f32x4 acc[4][4];
    #pragma unroll
    for (int i = 0; i < 4; ++i)
        #pragma unroll
        for (int j = 0; j < 4; ++j) acc[i][j] = 0.f;

    const char* Abase = (const char*)At + (size_t)bm * KB * TILEB;
    const char* Bbase = (const char*)Bt + (size_t)bn * KB * TILEB;

    #pragma unroll
    for (int i = 0; i < 4; ++i) {
        gload16(Abase + (size_t)w*4096 + i*1024 + lane*16, lds + w*4096 + i*1024);
        gload16(Bbase + (size_t)w*4096 + i*1024 + lane*16, lds + TILEB + w*4096 + i*1024);
    }
    asm volatile("s_waitcnt vmcnt(0)" ::: "memory");
    __syncthreads();

    int cur = 0;
    for (int kb = 0; kb < KB; ++kb) {
        char* Acur = lds + cur * (2*TILEB);
        char* Bcur = Acur + TILEB;
        if (kb + 1 < KB) {
            char* Anxt = lds + (cur ^ 1) * (2*TILEB);
            char* Bnxt = Anxt + TILEB;
            const char* an = Abase + (size_t)(kb+1)*TILEB + w*4096;
            const char* bsrc = Bbase + (size_t)(kb+1)*TILEB + w*4096;
            #pragma unroll
            for (int i = 0; i < 4; ++i) {
                gload16(an + i*1024 + lane*16, Anxt + w*4096 + i*1024);
                gload16(bsrc + i*1024 + lane*16, Bnxt + w*4096 + i*1024);
            }
        }
        short8 a0[4], a1[4], b0[4], b1[4];
        #pragma unroll
        for (int mi = 0; mi < 4; ++mi) {
            int row = wr*64 + mi*16 + r16;
            int sw = (row & 7) << 4;
            a0[mi] = *(const short8*)(Acur + ((row*128 + g*16) ^ sw));
            a1[mi] = *(const short8*)(Acur + ((row*128 + 64 + g*16) ^ sw));
        }
        #pragma unroll
        for (int ni = 0; ni < 4; ++ni) {
            int row = wc*64 + ni*16 + r16;
            int sw = (row & 7) << 4;
            b0[ni] = *(const short8*)(Bcur + ((row*128 + g*16) ^ sw));
            b1[ni] = *(const short8*)(Bcur + ((row*128 + 64 + g*16) ^ sw));
        }
        __builtin_amdgcn_s_setprio(1);
        #pragma unroll
        for (int mi = 0; mi < 4; ++mi)
            #pragma unroll
            for (int ni = 0; ni < 4; ++ni) {
                acc[mi][ni] = __builtin_amdgcn_mfma_f32_16x16x32_bf16(a0[mi], b0[ni], acc[mi][ni], 0, 0, 0);
                acc[mi][ni] = __builtin_amdgcn_mfma_f32_16x16x32_bf16(a1[mi], b1[ni], acc[mi][ni], 0, 0, 0);
            }
        __builtin_amdgcn_s_setprio(0);
        asm volatile("s_waitcnt vmcnt(0)" ::: "memory");
        __syncthreads();
        cur ^= 1;
    }

    int nq = bn*128 + wc*64;
    float bv[4];
    #pragma unroll
    for (int ni = 0; ni < 4; ++ni) {
        int n = nq + ni*16 + r16;
        bv[ni] = (MODE == 0) ? bias[(n < 1024) ? n : (n + 1024)] : bias[n];
    }
    #pragma unroll
    for (int mi = 0; mi < 4; ++mi) {
        #pragma unroll
        for (int rr = 0; rr < 4; ++rr) {
            int ml = wr*64 + mi*16 + 4*g + rr;
            int mg = bm*128 + ml;
            int bb = mg >> 10, tok = mg & 1023;
            #pragma unroll
            for (int ni = 0; ni < 4; ++ni) {
                int n = nq + ni*16 + r16;
                float v = acc[mi][ni][rr] + bv[ni];
                if (MODE == 0) {
                    if (n < 1024) {
                        unsigned short* qb = (unsigned short*)(outp + WS_QB);
                        int hh = n >> 6, d = n & 63;
                        qb[(((size_t)bb*16 + hh)*1024 + tok)*64 + d] = f2bf(v * QSCL);
                    } else {
                        float* vf = outp + WS_VF;
                        int hh = (n - 1024) >> 6, d = n & 63;
                        vf[(((size_t)bb*16 + hh)*1024 + tok)*64 + d] = v;
                    }
                } else {
                    outp[(size_t)mg*1024 + n] = v;
                }
            }
        }
    }
}

// ============================================================
// mean_dir / scores partials
// ============================================================
__global__ __launch_bounds__(256) void meandir_part(const float* __restrict__ past_k,
                                                    float* __restrict__ ws)
{
    int bh = blockIdx.x, seg = blockIdx.y, tid = threadIdx.x;
    const float* kpast = past_k + (size_t)bh * NPAST * DD;
    const float* knew  = ws + WS_KF + (size_t)bh * NN * DD;
    float dir[64];
    #pragma unroll
    for (int i = 0; i < 64; ++i) dir[i] = 0.f;

    int j0 = seg * 1024;
    for (int jj = tid; jj < 1024; jj += 256) {
        int pos = NANCH + j0 + jj;
        const float* row = (pos < NPAST) ? (kpast + (size_t)pos * DD)
                                         : (knew + (size_t)(pos - NPAST) * DD);
        float v[64]; float ss = 0.f;
        #pragma unroll
        for (int g = 0; g < 16; ++g) {
            float4 t = *(const float4*)&row[g*4];
            v[4*g]=t.x; v[4*g+1]=t.y; v[4*g+2]=t.z; v[4*g+3]=t.w;
            ss += t.x*t.x + t.y*t.y + t.z*t.z + t.w*t.w;
        }
        float inv = 1.0f / (sqrtf(ss) + 1e-6f);
        #pragma unroll
        for (int i = 0; i < 64; ++i) dir[i] += v[i] * inv;
    }
    #pragma unroll
    for (int i = 0; i < 64; ++i)
        for (int off = 32; off; off >>= 1) dir[i] += __shfl_xor(dir[i], off);

    __shared__ float sdir[4][64];
    int lane = tid & 63, wid = tid >> 6;
    if (lane == 0) {
        #pragma unroll
        for (int i = 0; i < 64; ++i) sdir[wid][i] = dir[i];
    }
    __syncthreads();
    if (tid < 64) {
        float s = sdir[0][tid] + sdir[1][tid] + sdir[2][tid] + sdir[3][tid];
        ws[WS_MDP + ((size_t)bh*8 + seg)*DD + tid] = s;
    }
}

__global__ void meandir_red(float* __restrict__ ws)
{
    int bh = blockIdx.x, tid = threadIdx.x;
    float s = 0.f;
    #pragma unroll
    for (int seg = 0; seg < 8; ++seg)
        s += ws[WS_MDP + ((size_t)bh*8 + seg)*DD + tid];
    ws[WS_MD + (size_t)bh*DD + tid] = s * (1.0f / (float)NCAND);
}

__global__ __launch_bounds__(256) void scores_part(const float* __restrict__ past_k,
                                                   float* __restrict__ ws)
{
    __shared__ float md[64];
    __shared__ float sred[4];
    int bh = blockIdx.x, seg = blockIdx.y, tid = threadIdx.x;
    if (tid < 64) md[tid] = ws[WS_MD + (size_t)bh*DD + tid];
    __syncthreads();
    const float* kpast = past_k + (size_t)bh * NPAST * DD;
    const float* knew  = ws + WS_KF + (size_t)bh * NN * DD;
    float ssum = 0.f;
    int j0 = seg * 1024;
    for (int jj = tid; jj < 1024; jj += 256) {
        int j = j0 + jj;
        int pos = NANCH + j;
        const float* row = (pos < NPAST) ? (kpast + (size_t)pos * DD)
                                         : (knew + (size_t)(pos - NPAST) * DD);
        float ss = 0.f, dp = 0.f;
        #pragma unroll
        for (int g = 0; g < 16; ++g) {
            float4 t = *(const float4*)&row[g*4];
            ss += t.x*t.x + t.y*t.y + t.z*t.z + t.w*t.w;
            dp += t.x*md[4*g] + t.y*md[4*g+1] + t.z*md[4*g+2] + t.w*md[4*g+3];
        }
        float sc = dp / (sqrtf(ss) + 1e-6f);
        ws[WS_SC + (size_t)bh*NCAND + j] = sc;
        ssum += sc;
    }
    for (int off = 32; off; off >>= 1) ssum += __shfl_xor(ssum, off);
    int lane = tid & 63, wid = tid >> 6;
    if (lane == 0) sred[wid] = ssum;
    __syncthreads();
    if (tid == 0)
        ws[WS_BSP + (size_t)bh*8 + seg] = sred[0] + sred[1] + sred[2] + sred[3];
}

// ============================================================
// topk: byte-histogram radix threshold + stable compaction.
// avg_scores folded in (block 0).
// ============================================================
__global__ __launch_bounds__(1024) void topk_k(float* __restrict__ ws, int* __restrict__ sel,
                                               float* __restrict__ dout)
{
    __shared__ unsigned keys[NCAND];
    __shared__ int hist[256];
    __shared__ int red[16];
    __shared__ int red2[16];
    __shared__ float fred[16];
    __shared__ int bcast;
    __shared__ unsigned bbyte;
    int bh = blockIdx.x, tid = threadIdx.x;
    int lane = tid & 63, wid = tid >> 6;

    // folded avg_scores (block 0 only)
    if (bh == 0) {
        float v = (tid < 256) ? ws[WS_BSP + tid] : 0.f;
        for (int off = 32; off; off >>= 1) v += __shfl_xor(v, off);
        if (lane == 0) fred[wid] = v;
        __syncthreads();
        if (tid == 0) {
            float s = 0.f;
            for (int i = 0; i < 16; ++i) s += fred[i];
            dout[AVG_OFF] = s * (1.0f / ((float)BH * (float)NCAND));
        }
        __syncthreads();
    }

    for (int j = tid; j < NCAND; j += 1024) {
        unsigned u = __float_as_uint(ws[WS_SC + (size_t)bh*NCAND + j]);
        u ^= (u & 0x80000000u) ? 0xFFFFFFFFu : 0x80000000u;
        keys[j] = u;
    }
    __syncthreads();

    int rem = NKEEP;
    unsigned prefix = 0;
    #pragma unroll
    for (int pass = 0; pass < 4; ++pass) {
        int shift = 24 - 8*pass;
        if (tid < 256) hist[tid] = 0;
        __syncthreads();
        unsigned himask = (pass == 0) ? 0u : (0xFFFFFFFFu << (shift + 8));
        for (int j = tid; j < NCAND; j += 1024) {
            unsigned k = keys[j];
            if ((k & himask) == prefix)
                atomicAdd(&hist[(k >> shift) & 255], 1);
        }
        __syncthreads();
        if (tid == 0) {
            int cum = 0, b = 0;
            for (; b < 255; ++b) {
                if (rem <= cum + hist[b]) break;
                cum += hist[b];
            }
            bcast = cum;
            bbyte = (unsigned)b;
        }
        __syncthreads();
        rem -= bcast;
        prefix |= (bbyte << shift);
        __syncthreads();
    }
    unsigned T = prefix;

    {
        int cnt = 0;
        for (int j = tid; j < NCAND; j += 1024) cnt += (int)(keys[j] < T);
        for (int off = 32; off; off >>= 1) cnt += __shfl_xor(cnt, off);
        if (lane == 0) red[wid] = cnt;
        __syncthreads();
        if (tid == 0) { int c = 0; for (int i = 0; i < 16; ++i) c += red[i]; bcast = c; }
        __syncthreads();
    }
    int c_less = bcast;
    int ttie = NKEEP - c_less;

    int base = tid * 8;
    unsigned kv[8]; int lcnt = 0, ecnt = 0;
    #pragma unroll
    for (int i = 0; i < 8; ++i) {
        kv[i] = keys[base + i];
        lcnt += (int)(kv[i] < T);
        ecnt += (int)(kv[i] == T);
    }
    int li = lcnt, ei = ecnt;
    for (int off = 1; off < 64; off <<= 1) {
        int tl = __shfl_up(li, off);
        int te = __shfl_up(ei, off);
        if (lane >= off) { li += tl; ei += te; }
    }
    __syncthreads();
    if (lane == 63) { red[wid] = li; red2[wid] = ei; }
    __syncthreads();
    int lb = 0, eb = 0;
    for (int w = 0; w < wid; ++w) { lb += red[w]; eb += red2[w]; }
    lb += li - lcnt; eb += ei - ecnt;
    #pragma unroll
    for (int i = 0; i < 8; ++i) {
        bool less = kv[i] < T, eq = kv[i] == T;
        if (less || (eq && eb < ttie)) {
            int pos = lb + (eb < ttie ? eb : ttie);
            sel[(size_t)bh*NKEEP + pos] = base + i;
        }
        lb += (int)less; eb += (int)eq;
    }
}

// ============================================================
// gather k_new / v_new (fp32, exact) into d_out
// ============================================================
__global__ __launch_bounds__(256) void gather_k(const float* __restrict__ past_k,
                                                const float* __restrict__ past_v,
                                                const float* __restrict__ ws,
                                                const int* __restrict__ sel,
                                                float* __restrict__ dout)
{
    int gid = blockIdx.x * 256 + threadIdx.x;
    int row = gid >> 4, lane = gid & 15;
    int bh = row >> 12, r = row & 4095;
    int pos = (r < NANCH) ? r : (NANCH + sel[(size_t)bh*NKEEP + (r - NANCH)]);
    const float *kr, *vr;
    if (pos < NPAST) {
        kr = past_k + ((size_t)bh*NPAST + pos) * DD;
        vr = past_v + ((size_t)bh*NPAST + pos) * DD;
    } else {
        kr = ws + WS_KF + ((size_t)bh*NN + (pos - NPAST)) * DD;
        vr = ws + WS_VF + ((size_t)bh*NN + (pos - NPAST)) * DD;
    }
    float4 kq = *(const float4*)&kr[lane*4];
    float4 vq = *(const float4*)&vr[lane*4];
    *(float4*)&dout[KNEW_OFF + ((size_t)bh*CBUD + r)*DD + lane*4] = kq;
    *(float4*)&dout[VNEW_OFF + ((size_t)bh*CBUD + r)*DD + lane*4] = vq;
}

// ============================================================
// merged: blocks <2048: V^T bf16 swizzled tiles from v_new;
// blocks >=2048: proj_w -> tiled bf16 (wpt).
// ============================================================
__global__ __launch_bounds__(256) void vtrans_conv(const float* __restrict__ dout,
                                                   unsigned short* __restrict__ vt,
                                                   const float* __restrict__ pw,
                                                   unsigned short* __restrict__ wpt)
{
    if (blockIdx.x >= 2048) {
        int gid = (blockIdx.x - 2048) * 256 + threadIdx.x;
        int r = gid >> 7, k0 = (gid & 127) * 8;
        float4 a = *(const float4*)&pw[(size_t)r * 1024 + k0];
        float4 b = *(const float4*)&pw[(size_t)r * 1024 + k0 + 4];
        uint4 u;
        u.x = cvtpk(a.x, a.y); u.y = cvtpk(a.z, a.w);
        u.z = cvtpk(b.x, b.y); u.w = cvtpk(b.z, b.w);
        size_t tile = (size_t)(r >> 7) * 16 + (k0 >> 6);
        int inner = (((r & 127) * 128 + (k0 & 63) * 2)) ^ ((r & 7) << 4);
        *(uint4*)((char*)wpt + tile * TILEB + inner) = u;
        return;
    }
    __shared__ unsigned short S[64][65];
    int bh = blockIdx.x >> 6, kt = blockIdx.x & 63;
    int c0 = kt * 64;
    int tid = threadIdx.x;
    int r = tid >> 2, c4 = (tid & 3) * 16;
    const float* src = dout + VNEW_OFF + ((size_t)bh*CBUD + c0 + r)*DD + c4;
    #pragma unroll
    for (int i = 0; i < 4; ++i) {
        float4 f = *(const float4*)&src[i*4];
        S[r][c4 + i*4 + 0] = f2bf(f.x);
        S[r][c4 + i*4 + 1] = f2bf(f.y);
        S[r][c4 + i*4 + 2] = f2bf(f.z);
        S[r][c4 + i*4 + 3] = f2bf(f.w);
    }
    __syncthreads();
    int d = r, k4 = c4;
    uint4 u0, u1;
    u0.x = (unsigned)S[k4+0][d] | ((unsigned)S[k4+1][d] << 16);
    u0.y = (unsigned)S[k4+2][d] | ((unsigned)S[k4+3][d] << 16);
    u0.z = (unsigned)S[k4+4][d] | ((unsigned)S[k4+5][d] << 16);
    u0.w = (unsigned)S[k4+6][d] | ((unsigned)S[k4+7][d] << 16);
    u1.x = (unsigned)S[k4+8][d] | ((unsigned)S[k4+9][d] << 16);
    u1.y = (unsigned)S[k4+10][d] | ((unsigned)S[k4+11][d] << 16);
    u1.z = (unsigned)S[k4+12][d] | ((unsigned)S[k4+13][d] << 16);
    u1.w = (unsigned)S[k4+14][d] | ((unsigned)S[k4+15][d] << 16);
    size_t tbase = ((size_t)bh*64 + kt) * 8192;
    int sw = (d & 7) << 4;
    *(uint4*)((char*)vt + tbase + ((d*128 + k4*2)      ^ sw)) = u0;
    *(uint4*)((char*)vt + tbase + ((d*128 + k4*2 + 16) ^ sw)) = u1;
}

// ============================================================
// MFMA flash attention, swapped QK^T, fixed-max softmax.
// 128-key iterations: two 64-key halves, double-buffered K/V,
// ONE barrier per 128 keys. V staged via gload16 DMA from
// pre-swizzled tiles; K reg-staged. 512 blocks x 4 waves.
// ============================================================
__global__ __launch_bounds__(256) void attn_mfma(const unsigned short* __restrict__ qb,
                                                 const float* __restrict__ dout,
                                                 const unsigned short* __restrict__ vt,
                                                 unsigned short* __restrict__ ot)
{
    __shared__ char kls[2][2][8192];
    __shared__ char vls[2][2][8192];
    __shared__ char pls[4][2048];

    int orig = blockIdx.x;
    int bid = (orig & 7) * 64 + (orig >> 3);
    int bh = bid >> 4, qt = bid & 15;
    int b = bh >> 4, h = bh & 15;
    int tid = threadIdx.x;
    int w = tid >> 6, lane = tid & 63;
    int g = lane >> 4, r16 = lane & 15;
    int q0 = qt * 64 + w * 16;

    const unsigned short* qrow = qb + ((size_t)bh*NN + q0 + r16) * DD;
    short8 qa0 = *(const short8*)&qrow[8*g];
    short8 qa1 = *(const short8*)&qrow[32 + 8*g];

    const float* kf = dout + KNEW_OFF + (size_t)bh * CBUD * DD;
    const char* vtt = (const char*)vt + (size_t)bh * 64 * 8192;
    char* plw = pls[w];
    int psw = (r16 & 7) << 4;

    // K staging map: 8 threads/row, 16B each; two row-slots per 64-tile
    int srA = tid >> 3;
    int srB = srA + 32;
    int scb = (tid & 7) * 16;
    int d0  = scb >> 1;
    int sdA = (srA*128 + scb) ^ ((srA & 7) << 4);
    int sdB = (srB*128 + scb) ^ ((srB & 7) << 4);

    f32x4 accd[4];
    #pragma unroll
    for (int dt = 0; dt < 4; ++dt) accd[dt] = 0.f;
    float lsum = 0.f;

    // prologue: stage 64-tiles 0,1 into buf 0
    {
        gload16(vtt + tid*16,               vls[0][0] + tid*16);
        gload16(vtt + 4096 + tid*16,        vls[0][0] + 4096 + tid*16);
        gload16(vtt + 8192 + tid*16,        vls[0][1] + tid*16);
        gload16(vtt + 8192 + 4096 + tid*16, vls[0][1] + 4096 + tid*16);
        #pragma unroll
        for (int hh = 0; hh < 2; ++hh) {
            const float* ksA = kf + ((size_t)hh*64 + srA) * DD + d0;
            const float* ksB = kf + ((size_t)hh*64 + srB) * DD + d0;
            float4 a0 = *(const float4*)ksA, a1 = *(const float4*)(ksA + 4);
            float4 b0 = *(const float4*)ksB, b1 = *(const float4*)(ksB + 4);
            uint4 kuA, kuB;
            kuA.x = cvtpk(a0.x,a0.y); kuA.y = cvtpk(a0.z,a0.w);
            kuA.z = cvtpk(a1.x,a1.y); kuA.w = cvtpk(a1.z,a1.w);
            kuB.x = cvtpk(b0.x,b0.y); kuB.y = cvtpk(b0.z,b0.w);
            kuB.z = cvtpk(b1.x,b1.y); kuB.w = cvtpk(b1.z,b1.w);
            *(uint4*)&kls[0][hh][sdA] = kuA;
            *(uint4*)&kls[0][hh][sdB] = kuB;
        }
    }
    __syncthreads();

    int cur = 0;
    for (int t = 0; t < 32; ++t) {
        float4 na0[2], na1[2], nb0[2], nb1[2];
        bool more = (t + 1 < 32);
        if (more) {
            int nt = 2*t + 2;
            gload16(vtt + (size_t)nt*8192 + tid*16,            vls[cur^1][0] + tid*16);
            gload16(vtt + (size_t)nt*8192 + 4096 + tid*16,     vls[cur^1][0] + 4096 + tid*16);
            gload16(vtt + (size_t)(nt+1)*8192 + tid*16,        vls[cur^1][1] + tid*16);
            gload16(vtt + (size_t)(nt+1)*8192 + 4096 + tid*16, vls[cur^1][1] + 4096 + tid*16);
            #pragma unroll
            for (int hh = 0; hh < 2; ++hh) {
                const float* ksA = kf + ((size_t)(nt+hh)*64 + srA) * DD + d0;
                const float* ksB = kf + ((size_t)(nt+hh)*64 + srB) * DD + d0;
                na0[hh] = *(const float4*)ksA; na1[hh] = *(const float4*)(ksA + 4);
                nb0[hh] = *(const float4*)ksB; nb1[hh] = *(const float4*)(ksB + 4);
            }
        }

        #pragma unroll
        for (int hh = 0; hh < 2; ++hh) {
            const char* kb = kls[cur][hh];
            f32x4 sacc[4];
            #pragma unroll
            for (int t4 = 0; t4 < 4; ++t4) sacc[t4] = 0.f;
            __builtin_amdgcn_s_setprio(1);
            #pragma unroll
            for (int t4 = 0; t4 < 4; ++t4) {
                int row = 16*t4 + r16;
                int sw = (r16 & 7) << 4;
                short8 ka0 = *(const short8*)(kb + ((row*128 + g*16) ^ sw));
                short8 ka1 = *(const short8*)(kb + ((row*128 + 64 + g*16) ^ sw));
                sacc[t4] = __builtin_amdgcn_mfma_f32_16x16x32_bf16(ka0, qa0, sacc[t4], 0, 0, 0);
                sacc[t4] = __builtin_amdgcn_mfma_f32_16x16x32_bf16(ka1, qa1, sacc[t4], 0, 0, 0);
            }
            __builtin_amdgcn_s_setprio(0);

            float p[4][4];
            float ps = 0.f;
            #pragma unroll
            for (int t4 = 0; t4 < 4; ++t4) {
                p[t4][0] = fexp2(sacc[t4][0]);
                p[t4][1] = fexp2(sacc[t4][1]);
                p[t4][2] = fexp2(sacc[t4][2]);
                p[t4][3] = fexp2(sacc[t4][3]);
                ps += (p[t4][0] + p[t4][1]) + (p[t4][2] + p[t4][3]);
            }
            lsum += ps;
            #pragma unroll
            for (int t4 = 0; t4 < 4; ++t4) {
                uint2 u;
                u.x = cvtpk(p[t4][0], p[t4][1]);
                u.y = cvtpk(p[t4][2], p[t4][3]);
                int cb = (16*t4 + 4*g) * 2;
                *(uint2*)&plw[(r16*128 + cb) ^ psw] = u;
            }

            short8 pa0 = *(const short8*)&plw[(r16*128 + 16*g)      ^ psw];
            short8 pa1 = *(const short8*)&plw[(r16*128 + 64 + 16*g) ^ psw];
            const char* vb = vls[cur][hh];
            __builtin_amdgcn_s_setprio(1);
            #pragma unroll
            for (int dt = 0; dt < 4; ++dt) {
                int row = dt*16 + r16;
                int sw = (r16 & 7) << 4;
                short8 vb0 = *(const short8*)(vb + ((row*128 + g*16) ^ sw));
                short8 vb1 = *(const short8*)(vb + ((row*128 + 64 + g*16) ^ sw));
                accd[dt] = __builtin_amdgcn_mfma_f32_16x16x32_bf16(pa0, vb0, accd[dt], 0, 0, 0);
                accd[dt] = __builtin_amdgcn_mfma_f32_16x16x32_bf16(pa1, vb1, accd[dt], 0, 0, 0);
            }
            __builtin_amdgcn_s_setprio(0);
        }

        if (more) {
            #pragma unroll
            for (int hh = 0; hh < 2; ++hh) {
                uint4 kuA, kuB;
                kuA.x = cvtpk(na0[hh].x, na0[hh].y); kuA.y = cvtpk(na0[hh].z, na0[hh].w);
                kuA.z = cvtpk(na1[hh].x, na1[hh].y); kuA.w = cvtpk(na1[hh].z, na1[hh].w);
                kuB.x = cvtpk(nb0[hh].x, nb0[hh].y); kuB.y = cvtpk(nb0[hh].z, nb0[hh].w);
                kuB.z = cvtpk(nb1[hh].x, nb1[hh].y); kuB.w = cvtpk(nb1[hh].z, nb1[hh].w);
                *(uint4*)&kls[cur^1][hh][sdA] = kuA;
                *(uint4*)&kls[cur^1][hh][sdB] = kuB;
            }
        }
        __syncthreads();   // drains gload_lds (vmcnt) + ds_writes
        cur ^= 1;
    }

    // epilogue: one cross-lane l reduce, normalize + OT write
    lsum += __shfl_xor(lsum, 16);
    lsum += __shfl_xor(lsum, 32);
    float ivl = 1.0f / lsum;               // valid for q = r16
    float iq[4];
    #pragma unroll
    for (int rr = 0; rr < 4; ++rr) iq[rr] = __shfl(ivl, 20*g + rr);
    #pragma unroll
    for (int dt = 0; dt < 4; ++dt) {
        #pragma unroll
        for (int rr = 0; rr < 4; ++rr) {
            int q = q0 + 4*g + rr;
            int mrow = b*1024 + q;
            int d = dt*16 + r16;
            size_t tile = (size_t)(mrow >> 7) * 16 + h;
            int inner = ((mrow & 127)*128 + d*2) ^ ((mrow & 7) << 4);
            *(unsigned short*)((char*)ot + tile*TILEB + inner) = f2bf(accd[dt][rr] * iq[rr]);
        }
    }
}

// ============================================================
extern "C" void kernel_launch(void* const* d_in, const int* in_sizes, int n_in,
                              void* d_out, int out_size, void* d_ws, size_t ws_size,
                              hipStream_t stream)
{
    (void)in_sizes; (void)n_in; (void)out_size; (void)ws_size;
    const float* x      = (const float*)d_in[0];
    const float* past_k = (const float*)d_in[1];
    const float* past_v = (const float*)d_in[2];
    const float* qkv_w  = (const float*)d_in[3];
    const float* qkv_b  = (const float*)d_in[4];
    const float* proj_w = (const float*)d_in[5];
    const float* proj_b = (const float*)d_in[6];
    float* out = (float*)d_out;
    float* ws  = (float*)d_ws;
    int*   sel = (int*)(ws + WS_SEL);
    unsigned short* xt   = (unsigned short*)(ws + WS_XT);
    unsigned short* wqvt = (unsigned short*)(ws + WS_WQVT);
    unsigned short* wpt  = (unsigned short*)(ws + WS_WPT);
    unsigned short* qbp  = (unsigned short*)(ws + WS_QB);
    unsigned short* vtp  = (unsigned short*)(ws + WS_VTS);
    unsigned short* otp  = (unsigned short*)(ws + WS_OT);

    conv_xw<<<2048, 256, 0, stream>>>(x, qkv_w, xt, wqvt);
    kf_gemm<<<dim3(16, 32), 256, 0, stream>>>(x, qkv_w, qkv_b, ws);
    mfma_gemm<0><<<dim3(16, 16), 256, 0, stream>>>(xt, wqvt, qkv_b, ws);
    meandir_part<<<dim3(32, 8), 256, 0, stream>>>(past_k, ws);
    meandir_red<<<32, 64, 0, stream>>>(ws);
    scores_part<<<dim3(32, 8), 256, 0, stream>>>(past_k, ws);
    topk_k<<<32, 1024, 0, stream>>>(ws, sel, out);
    gather_k<<<8192, 256, 0, stream>>>(past_k, past_v, ws, sel, out);
    vtrans_conv<<<2560, 256, 0, stream>>>(out, vtp, proj_w, wpt);
    attn_mfma<<<512, 256, 0, stream>>>(qbp, out, vtp, otp);
    mfma_gemm<1><<<dim3(8, 16), 256, 0, stream>>>(otp, wpt, proj_b, out);
}